// Round 6
// baseline (834.727 us; speedup 1.0000x reference)
//
#include <hip/hip_runtime.h>
#include <hip/hip_bf16.h>
#include <stdint.h>

#define NTOK 49
#define SCALE 0.17677669529663687f

typedef __attribute__((ext_vector_type(8))) short bf16x8;
typedef __attribute__((ext_vector_type(4))) float f32x4;

__device__ __forceinline__ unsigned short f2bf(float f) {
    union { float f; unsigned int u; } v; v.f = f;
    unsigned int r = v.u + 0x7FFFu + ((v.u >> 16) & 1u);
    return (unsigned short)(r >> 16);
}

__device__ __forceinline__ uint32_t pkbf(float lo, float hi) {
    __hip_bfloat162 h = __float22bfloat162_rn(float2{lo, hi});
    union { __hip_bfloat162 h; uint32_t u; } c; c.h = h;
    return c.u;
}

// ---- prep: bf16 weights (Q rows pre-scaled), transposed+masked bias table,
// ---- scaled qkv bias copy ----
__global__ void prep_kernel(const float* __restrict__ qkv_w,
                            const float* __restrict__ proj_w,
                            const float* __restrict__ bias_table,
                            const float* __restrict__ qkv_b,
                            unsigned short* __restrict__ w_qkv,
                            unsigned short* __restrict__ w_proj,
                            float* __restrict__ bias_t,
                            float* __restrict__ sbias) {
    const int total = 196608 + 65536 + 32768 + 768;
    for (int i = blockIdx.x * blockDim.x + threadIdx.x; i < total;
         i += gridDim.x * blockDim.x) {
        if (i < 196608) {
            float s = (i < 65536) ? SCALE : 1.0f;   // Q rows pre-scaled
            w_qkv[i] = f2bf(qkv_w[i] * s);
        } else if (i < 262144) {
            w_proj[i - 196608] = f2bf(proj_w[i - 196608]);
        } else if (i < 294912) {
            int idx = i - 262144;
            int hh = idx >> 12;             // head
            int j  = (idx >> 6) & 63;       // key token (row)
            int ii = idx & 63;              // query token (col)
            float v;
            if (j >= NTOK)       v = -1e30f;            // mask padded keys
            else if (ii >= NTOK) v = 0.0f;              // garbage queries: finite
            else {
                int rel = (ii / 7 - j / 7 + 6) * 13 + (ii % 7 - j % 7 + 6);
                v = bias_table[rel * 8 + hh];
            }
            bias_t[idx] = v;
        } else {
            int r = i - 294912;
            sbias[r] = qkv_b[r] * (r < 256 ? SCALE : 1.0f);
        }
    }
}

// ---- fused window attention: one window/block, 8 waves, 1 head/wave ----
// LDS: sX [64][264] bf16 (33792 B, reused as sO) + per-wave scratch [64][36]
// bf16 (4608 B x 8 = 36864 B). Total 70656 B -> 2 blocks/CU.
// Register budget: peak ~110 (acc<=32 AGPR everywhere) -> no spills at the
// launch_bounds(512,4) cap of 128.
__global__ __launch_bounds__(512, 4) void wattn_kernel(
    const float* __restrict__ x,
    const unsigned short* __restrict__ w_qkv,
    const unsigned short* __restrict__ w_proj,
    const float* __restrict__ bias_t,
    const float* __restrict__ sbias,
    const float* __restrict__ proj_b,
    float* __restrict__ out)
{
    extern __shared__ char smem[];
    unsigned short* sX = (unsigned short*)smem;       // 64*264 elems
    unsigned short* scrBase = sX + 64 * 264;

    const int tid  = threadIdx.x;
    const int wv   = tid >> 6;
    const int lane = tid & 63;
    const int l16  = lane & 15;
    const int g    = lane >> 4;
    const int lk   = g * 8;

    unsigned short* scr = scrBase + wv * (64 * 36);   // [64][36] per wave
    unsigned short* sO  = sX;
    const int b = blockIdx.x;
    const int h = wv;
    const f32x4 fz = {0.f, 0.f, 0.f, 0.f};

    // ---------- stage x -> LDS bf16, zero pad rows ----------
    const float* xb = x + (size_t)b * (NTOK * 256);
    for (int it = tid * 4; it < NTOK * 256; it += 512 * 4) {
        float4 v = *(const float4*)(xb + it);
        int r = it >> 8, c = it & 255;
        uint2 u = make_uint2(pkbf(v.x, v.y), pkbf(v.z, v.w));
        *(uint2*)(sX + r * 264 + c) = u;
    }
    for (int it = tid * 4; it < 15 * 256; it += 512 * 4) {
        int r = 49 + (it >> 8), c = it & 255;
        *(uint2*)(sX + r * 264 + c) = make_uint2(0, 0);
    }
    __syncthreads();

    bf16x8 qf[4], kf[4], vf[2][2];

    // ---------- Q-GEMM (transposed: C = Q^T tiles, 32 feat x 64 tok) ----------
    {
        f32x4 acc[2][4];
        #pragma unroll
        for (int mt = 0; mt < 2; ++mt)
            #pragma unroll
            for (int nt = 0; nt < 4; ++nt) acc[mt][nt] = fz;

        for (int kb = 0; kb < 8; ++kb) {
            bf16x8 bx[4];
            #pragma unroll
            for (int nt = 0; nt < 4; ++nt)
                bx[nt] = *(const bf16x8*)(sX + (nt * 16 + l16) * 264 + kb * 32 + lk);
            #pragma unroll
            for (int mt = 0; mt < 2; ++mt) {
                bf16x8 aw = *(const bf16x8*)(w_qkv + (h * 32 + mt * 16 + l16) * 256 + kb * 32 + lk);
                #pragma unroll
                for (int nt = 0; nt < 4; ++nt)
                    acc[mt][nt] = __builtin_amdgcn_mfma_f32_16x16x32_bf16(
                        aw, bx[nt], acc[mt][nt], 0, 0, 0);
            }
        }
        // Q bias (pre-scaled)
        float4 bq0 = *(const float4*)(sbias + h * 32 + 4 * g);
        float4 bq1 = *(const float4*)(sbias + h * 32 + 16 + 4 * g);
        #pragma unroll
        for (int nt = 0; nt < 4; ++nt) {
            acc[0][nt][0] += bq0.x; acc[0][nt][1] += bq0.y;
            acc[0][nt][2] += bq0.z; acc[0][nt][3] += bq0.w;
            acc[1][nt][0] += bq1.x; acc[1][nt][1] += bq1.y;
            acc[1][nt][2] += bq1.z; acc[1][nt][3] += bq1.w;
        }
        // bounce: [token 0..63][feat 0..31] in scr[64][36], single round
        #pragma unroll
        for (int nt = 0; nt < 4; ++nt)
            #pragma unroll
            for (int mt = 0; mt < 2; ++mt) {
                uint2 d = make_uint2(pkbf(acc[mt][nt][0], acc[mt][nt][1]),
                                     pkbf(acc[mt][nt][2], acc[mt][nt][3]));
                *(uint2*)(scr + (nt * 16 + l16) * 36 + mt * 16 + 4 * g) = d;
            }
        #pragma unroll
        for (int nt = 0; nt < 4; ++nt)
            qf[nt] = *(const bf16x8*)(scr + (nt * 16 + l16) * 36 + lk);
    }

    // ---------- K-GEMM (same shape; WAR vs Q reads separated by GEMM) ----------
    {
        f32x4 acc[2][4];
        #pragma unroll
        for (int mt = 0; mt < 2; ++mt)
            #pragma unroll
            for (int nt = 0; nt < 4; ++nt) acc[mt][nt] = fz;

        for (int kb = 0; kb < 8; ++kb) {
            bf16x8 bx[4];
            #pragma unroll
            for (int nt = 0; nt < 4; ++nt)
                bx[nt] = *(const bf16x8*)(sX + (nt * 16 + l16) * 264 + kb * 32 + lk);
            #pragma unroll
            for (int mt = 0; mt < 2; ++mt) {
                bf16x8 aw = *(const bf16x8*)(w_qkv + (256 + h * 32 + mt * 16 + l16) * 256 + kb * 32 + lk);
                #pragma unroll
                for (int nt = 0; nt < 4; ++nt)
                    acc[mt][nt] = __builtin_amdgcn_mfma_f32_16x16x32_bf16(
                        aw, bx[nt], acc[mt][nt], 0, 0, 0);
            }
        }
        // K bias dropped (softmax-invariant)
        #pragma unroll
        for (int nt = 0; nt < 4; ++nt)
            #pragma unroll
            for (int mt = 0; mt < 2; ++mt) {
                uint2 d = make_uint2(pkbf(acc[mt][nt][0], acc[mt][nt][1]),
                                     pkbf(acc[mt][nt][2], acc[mt][nt][3]));
                *(uint2*)(scr + (nt * 16 + l16) * 36 + mt * 16 + 4 * g) = d;
            }
        #pragma unroll
        for (int nt = 0; nt < 4; ++nt)
            kf[nt] = *(const bf16x8*)(scr + (nt * 16 + l16) * 36 + lk);
    }

    // ---------- V-GEMM (normal: C = V, 64 tok x 32 d) ----------
    {
        f32x4 acc[4][2];
        #pragma unroll
        for (int rt = 0; rt < 4; ++rt) { acc[rt][0] = fz; acc[rt][1] = fz; }

        for (int kb = 0; kb < 8; ++kb) {
            bf16x8 ax[4];
            #pragma unroll
            for (int rt = 0; rt < 4; ++rt)
                ax[rt] = *(const bf16x8*)(sX + (rt * 16 + l16) * 264 + kb * 32 + lk);
            #pragma unroll
            for (int ct = 0; ct < 2; ++ct) {
                bf16x8 bw = *(const bf16x8*)(w_qkv + (512 + h * 32 + ct * 16 + l16) * 256 + kb * 32 + lk);
                #pragma unroll
                for (int rt = 0; rt < 4; ++rt)
                    acc[rt][ct] = __builtin_amdgcn_mfma_f32_16x16x32_bf16(
                        ax[rt], bw, acc[rt][ct], 0, 0, 0);
            }
        }
        // V^T bounce: rows = kk*32 + d (disjoint halves, no WAR), cols = tok%32
        #pragma unroll
        for (int rt = 0; rt < 4; ++rt)
            #pragma unroll
            for (int ct = 0; ct < 2; ++ct) {
                uint2 d = make_uint2(pkbf(acc[rt][ct][0], acc[rt][ct][1]),
                                     pkbf(acc[rt][ct][2], acc[rt][ct][3]));
                *(uint2*)(scr + ((rt >> 1) * 32 + ct * 16 + l16) * 36 + (rt & 1) * 16 + 4 * g) = d;
            }
        #pragma unroll
        for (int dm = 0; dm < 2; ++dm)
            #pragma unroll
            for (int kk = 0; kk < 2; ++kk)
                vf[dm][kk] = *(const bf16x8*)(scr + (kk * 32 + dm * 16 + l16) * 36 + lk);
    }
    __syncthreads();   // all sX reads done; sO overlay now safe

    // ---------- attention (barrier-free, per-wave head), 2 query halves ----------
    const float* bt_h = bias_t + h * 4096;
    float4 bv0 = *(const float4*)(sbias + 512 + h * 32 + 4 * g);
    float4 bv1 = *(const float4*)(sbias + 512 + h * 32 + 16 + 4 * g);

    #pragma unroll
    for (int hf = 0; hf < 2; ++hf) {
        // S^T acc init from pre-masked bias, then 8 mfma
        f32x4 s[4][2];
        #pragma unroll
        for (int tr = 0; tr < 4; ++tr)
            #pragma unroll
            for (int tl = 0; tl < 2; ++tl) {
                const int i = (hf * 2 + tl) * 16 + l16;
                #pragma unroll
                for (int r = 0; r < 4; ++r)
                    s[tr][tl][r] = bt_h[(tr * 16 + 4 * g + r) * 64 + i];
            }
        #pragma unroll
        for (int tr = 0; tr < 4; ++tr)
            #pragma unroll
            for (int tl = 0; tl < 2; ++tl)
                s[tr][tl] = __builtin_amdgcn_mfma_f32_16x16x32_bf16(
                    kf[tr], qf[hf * 2 + tl], s[tr][tl], 0, 0, 0);

        // column-i softmax: tree-reduce 16 local values + 2 shfl_xor
        float inv[2];
        #pragma unroll
        for (int tl = 0; tl < 2; ++tl) {
            float m4[4];
            #pragma unroll
            for (int tr = 0; tr < 4; ++tr)
                m4[tr] = fmaxf(fmaxf(s[tr][tl][0], s[tr][tl][1]),
                               fmaxf(s[tr][tl][2], s[tr][tl][3]));
            float mx = fmaxf(fmaxf(m4[0], m4[1]), fmaxf(m4[2], m4[3]));
            mx = fmaxf(mx, __shfl_xor(mx, 16));
            mx = fmaxf(mx, __shfl_xor(mx, 32));
            float s4[4];
            #pragma unroll
            for (int tr = 0; tr < 4; ++tr) {
                float e0 = __expf(s[tr][tl][0] - mx);
                float e1 = __expf(s[tr][tl][1] - mx);
                float e2 = __expf(s[tr][tl][2] - mx);
                float e3 = __expf(s[tr][tl][3] - mx);
                s[tr][tl][0] = e0; s[tr][tl][1] = e1;
                s[tr][tl][2] = e2; s[tr][tl][3] = e3;
                s4[tr] = (e0 + e1) + (e2 + e3);
            }
            float sum = (s4[0] + s4[1]) + (s4[2] + s4[3]);
            sum += __shfl_xor(sum, 16);
            sum += __shfl_xor(sum, 32);
            inv[tl] = 1.0f / sum;
        }

        // P bounce: rows = kk*32 + i (disjoint halves), cols = j%32
        #pragma unroll
        for (int tr = 0; tr < 4; ++tr)
            #pragma unroll
            for (int tl = 0; tl < 2; ++tl) {
                uint2 d = make_uint2(pkbf(s[tr][tl][0], s[tr][tl][1]),
                                     pkbf(s[tr][tl][2], s[tr][tl][3]));
                *(uint2*)(scr + ((tr >> 1) * 32 + tl * 16 + l16) * 36 + (tr & 1) * 16 + 4 * g) = d;
            }
        bf16x8 pf[2][2];
        #pragma unroll
        for (int tl = 0; tl < 2; ++tl)
            #pragma unroll
            for (int kk = 0; kk < 2; ++kk)
                pf[tl][kk] = *(const bf16x8*)(scr + (kk * 32 + tl * 16 + l16) * 36 + lk);

        // O^T = V^T P  (unnormalized P; scale by inv afterwards)
        f32x4 o[2][2];
        #pragma unroll
        for (int dm = 0; dm < 2; ++dm) { o[dm][0] = fz; o[dm][1] = fz; }
        #pragma unroll
        for (int dm = 0; dm < 2; ++dm)
            #pragma unroll
            for (int tl = 0; tl < 2; ++tl)
                #pragma unroll
                for (int kk = 0; kk < 2; ++kk)
                    o[dm][tl] = __builtin_amdgcn_mfma_f32_16x16x32_bf16(
                        vf[dm][kk], pf[tl][kk], o[dm][tl], 0, 0, 0);

        // epilogue: *inv, +bv, pack, write O rows into sO
        #pragma unroll
        for (int dm = 0; dm < 2; ++dm) {
            const float4 bv = dm ? bv1 : bv0;
            #pragma unroll
            for (int tl = 0; tl < 2; ++tl) {
                const float iv = inv[tl];
                float r0 = o[dm][tl][0] * iv + bv.x;
                float r1 = o[dm][tl][1] * iv + bv.y;
                float r2 = o[dm][tl][2] * iv + bv.z;
                float r3 = o[dm][tl][3] * iv + bv.w;
                uint2 d = make_uint2(pkbf(r0, r1), pkbf(r2, r3));
                *(uint2*)(sO + ((hf * 2 + tl) * 16 + l16) * 264 + h * 32 + dm * 16 + 4 * g) = d;
            }
        }
    }
    __syncthreads();

    // ---------- proj GEMM (64x256, K=256), wave owns 32 cols ----------
    {
        f32x4 acc[4][2];
        #pragma unroll
        for (int rt = 0; rt < 4; ++rt) { acc[rt][0] = fz; acc[rt][1] = fz; }

        const int colbase = wv * 32;
        for (int kb = 0; kb < 8; ++kb) {
            bf16x8 a[4];
            #pragma unroll
            for (int rt = 0; rt < 4; ++rt)
                a[rt] = *(const bf16x8*)(sO + (rt * 16 + l16) * 264 + kb * 32 + lk);
            #pragma unroll
            for (int c = 0; c < 2; ++c) {
                bf16x8 bw = *(const bf16x8*)(w_proj + (colbase + c * 16 + l16) * 256 + kb * 32 + lk);
                #pragma unroll
                for (int rt = 0; rt < 4; ++rt)
                    acc[rt][c] = __builtin_amdgcn_mfma_f32_16x16x32_bf16(
                        a[rt], bw, acc[rt][c], 0, 0, 0);
            }
        }
        float* ob = out + (size_t)b * (NTOK * 256);
        #pragma unroll
        for (int c = 0; c < 2; ++c) {
            const int col = colbase + c * 16 + l16;
            const float pb = proj_b[col];
            #pragma unroll
            for (int rt = 0; rt < 4; ++rt)
                #pragma unroll
                for (int r = 0; r < 4; ++r) {
                    const int row = rt * 16 + 4 * g + r;
                    if (row < NTOK) ob[row * 256 + col] = acc[rt][c][r] + pb;
                }
        }
    }
}

extern "C" void kernel_launch(void* const* d_in, const int* in_sizes, int n_in,
                              void* d_out, int out_size, void* d_ws, size_t ws_size,
                              hipStream_t stream) {
    const float* x          = (const float*)d_in[0];
    const float* qkv_w      = (const float*)d_in[1];
    const float* qkv_b      = (const float*)d_in[2];
    const float* proj_w     = (const float*)d_in[3];
    const float* proj_b     = (const float*)d_in[4];
    const float* bias_table = (const float*)d_in[5];

    unsigned short* w_qkv  = (unsigned short*)d_ws;      // 196608 bf16
    unsigned short* w_proj = w_qkv + 196608;             // 65536 bf16
    float*          bias_t = (float*)(w_proj + 65536);   // 32768 f32
    float*          sbias  = bias_t + 32768;             // 768 f32

    prep_kernel<<<288, 256, 0, stream>>>(qkv_w, proj_w, bias_table, qkv_b,
                                         w_qkv, w_proj, bias_t, sbias);

    const int SMEM = (64 * 264 + 8 * 64 * 36) * 2;       // 70656 B
    hipFuncSetAttribute(reinterpret_cast<const void*>(wattn_kernel),
                        hipFuncAttributeMaxDynamicSharedMemorySize, SMEM);

    wattn_kernel<<<8192, 512, SMEM, stream>>>(x, w_qkv, w_proj, bias_t, sbias,
                                              proj_b, (float*)d_out);
}

// Round 7
// 646.810 us; speedup vs baseline: 1.2905x; 1.2905x over previous
//
#include <hip/hip_runtime.h>
#include <hip/hip_bf16.h>
#include <stdint.h>

#define NTOK 49
#define SCALE 0.17677669529663687f

typedef __attribute__((ext_vector_type(8))) short bf16x8;
typedef __attribute__((ext_vector_type(4))) float f32x4;

__device__ __forceinline__ unsigned short f2bf(float f) {
    union { float f; unsigned int u; } v; v.f = f;
    unsigned int r = v.u + 0x7FFFu + ((v.u >> 16) & 1u);
    return (unsigned short)(r >> 16);
}

__device__ __forceinline__ uint32_t pkbf(float lo, float hi) {
    __hip_bfloat162 h = __float22bfloat162_rn(float2{lo, hi});
    union { __hip_bfloat162 h; uint32_t u; } c; c.h = h;
    return c.u;
}

// ---- prep: bf16 weights (Q rows pre-scaled), bias in [h][j/4][i][j%4]
// ---- layout (one dwordx4 per S-tile-row init), scaled qkv bias copy ----
__global__ void prep_kernel(const float* __restrict__ qkv_w,
                            const float* __restrict__ proj_w,
                            const float* __restrict__ bias_table,
                            const float* __restrict__ qkv_b,
                            unsigned short* __restrict__ w_qkv,
                            unsigned short* __restrict__ w_proj,
                            float* __restrict__ bias_p,
                            float* __restrict__ sbias) {
    const int total = 196608 + 65536 + 32768 + 768;
    for (int i = blockIdx.x * blockDim.x + threadIdx.x; i < total;
         i += gridDim.x * blockDim.x) {
        if (i < 196608) {
            float s = (i < 65536) ? SCALE : 1.0f;   // Q rows pre-scaled
            w_qkv[i] = f2bf(qkv_w[i] * s);
        } else if (i < 262144) {
            w_proj[i - 196608] = f2bf(proj_w[i - 196608]);
        } else if (i < 294912) {
            int idx = i - 262144;
            int hh = idx >> 12;             // head
            int j  = (idx >> 6) & 63;       // key token
            int ii = idx & 63;              // query token
            float v;
            if (j >= NTOK)       v = -1e30f;            // mask padded keys
            else if (ii >= NTOK) v = 0.0f;              // garbage queries: finite
            else {
                int rel = (ii / 7 - j / 7 + 6) * 13 + (ii % 7 - j % 7 + 6);
                v = bias_table[rel * 8 + hh];
            }
            // layout: [h][j>>2][ii][j&3]  -> float4 over r=j&3
            bias_p[hh * 4096 + (j >> 2) * 256 + ii * 4 + (j & 3)] = v;
        } else {
            int r = i - 294912;
            sbias[r] = qkv_b[r] * (r < 256 ? SCALE : 1.0f);
        }
    }
}

// ---- fused window attention: one window/block, 8 waves, 1 head/wave ----
// LDS: sX [64][264] bf16 (33792 B, reused as sO) + per-wave scratch [64][36]
// bf16 (4608 B x 8). Total 70656 B -> 2 blocks/CU. Reg cap 128 (VGPR+AGPR);
// kb loops unroll-limited to keep hoisted loads from spilling past the cap.
__global__ __launch_bounds__(512, 4) void wattn_kernel(
    const float* __restrict__ x,
    const unsigned short* __restrict__ w_qkv,
    const unsigned short* __restrict__ w_proj,
    const float* __restrict__ bias_p,
    const float* __restrict__ sbias,
    const float* __restrict__ proj_b,
    float* __restrict__ out)
{
    extern __shared__ char smem[];
    unsigned short* sX = (unsigned short*)smem;       // 64*264 elems
    unsigned short* scrBase = sX + 64 * 264;

    const int tid  = threadIdx.x;
    const int wv   = tid >> 6;
    const int lane = tid & 63;
    const int l16  = lane & 15;
    const int g    = lane >> 4;
    const int lk   = g * 8;

    unsigned short* scr = scrBase + wv * (64 * 36);   // [64][36] per wave
    unsigned short* sO  = sX;
    const int b = blockIdx.x;
    const int h = wv;
    const f32x4 fz = {0.f, 0.f, 0.f, 0.f};

    // ---------- stage x -> LDS bf16, zero pad rows ----------
    const float* xb = x + (size_t)b * (NTOK * 256);
    for (int it = tid * 4; it < NTOK * 256; it += 512 * 4) {
        float4 v = *(const float4*)(xb + it);
        int r = it >> 8, c = it & 255;
        uint2 u = make_uint2(pkbf(v.x, v.y), pkbf(v.z, v.w));
        *(uint2*)(sX + r * 264 + c) = u;
    }
    for (int it = tid * 4; it < 15 * 256; it += 512 * 4) {
        int r = 49 + (it >> 8), c = it & 255;
        *(uint2*)(sX + r * 264 + c) = make_uint2(0, 0);
    }
    __syncthreads();

    bf16x8 qf[4], kf[4], vf[2][2];

    // ---------- Q-GEMM (transposed: C = Q^T tiles, 32 feat x 64 tok) ----------
    {
        f32x4 acc[2][4];
        #pragma unroll
        for (int mt = 0; mt < 2; ++mt)
            #pragma unroll
            for (int nt = 0; nt < 4; ++nt) acc[mt][nt] = fz;

        #pragma unroll 2
        for (int kb = 0; kb < 8; ++kb) {
            bf16x8 bx[4];
            #pragma unroll
            for (int nt = 0; nt < 4; ++nt)
                bx[nt] = *(const bf16x8*)(sX + (nt * 16 + l16) * 264 + kb * 32 + lk);
            #pragma unroll
            for (int mt = 0; mt < 2; ++mt) {
                bf16x8 aw = *(const bf16x8*)(w_qkv + (h * 32 + mt * 16 + l16) * 256 + kb * 32 + lk);
                #pragma unroll
                for (int nt = 0; nt < 4; ++nt)
                    acc[mt][nt] = __builtin_amdgcn_mfma_f32_16x16x32_bf16(
                        aw, bx[nt], acc[mt][nt], 0, 0, 0);
            }
        }
        // Q bias (pre-scaled)
        float4 bq0 = *(const float4*)(sbias + h * 32 + 4 * g);
        float4 bq1 = *(const float4*)(sbias + h * 32 + 16 + 4 * g);
        #pragma unroll
        for (int nt = 0; nt < 4; ++nt) {
            acc[0][nt][0] += bq0.x; acc[0][nt][1] += bq0.y;
            acc[0][nt][2] += bq0.z; acc[0][nt][3] += bq0.w;
            acc[1][nt][0] += bq1.x; acc[1][nt][1] += bq1.y;
            acc[1][nt][2] += bq1.z; acc[1][nt][3] += bq1.w;
        }
        // bounce: [token 0..63][feat 0..31] in scr[64][36], single round
        #pragma unroll
        for (int nt = 0; nt < 4; ++nt)
            #pragma unroll
            for (int mt = 0; mt < 2; ++mt) {
                uint2 d = make_uint2(pkbf(acc[mt][nt][0], acc[mt][nt][1]),
                                     pkbf(acc[mt][nt][2], acc[mt][nt][3]));
                *(uint2*)(scr + (nt * 16 + l16) * 36 + mt * 16 + 4 * g) = d;
            }
        #pragma unroll
        for (int nt = 0; nt < 4; ++nt)
            qf[nt] = *(const bf16x8*)(scr + (nt * 16 + l16) * 36 + lk);
    }

    // ---------- K-GEMM (same shape; WAR vs Q reads separated by GEMM) ----------
    {
        f32x4 acc[2][4];
        #pragma unroll
        for (int mt = 0; mt < 2; ++mt)
            #pragma unroll
            for (int nt = 0; nt < 4; ++nt) acc[mt][nt] = fz;

        #pragma unroll 2
        for (int kb = 0; kb < 8; ++kb) {
            bf16x8 bx[4];
            #pragma unroll
            for (int nt = 0; nt < 4; ++nt)
                bx[nt] = *(const bf16x8*)(sX + (nt * 16 + l16) * 264 + kb * 32 + lk);
            #pragma unroll
            for (int mt = 0; mt < 2; ++mt) {
                bf16x8 aw = *(const bf16x8*)(w_qkv + (256 + h * 32 + mt * 16 + l16) * 256 + kb * 32 + lk);
                #pragma unroll
                for (int nt = 0; nt < 4; ++nt)
                    acc[mt][nt] = __builtin_amdgcn_mfma_f32_16x16x32_bf16(
                        aw, bx[nt], acc[mt][nt], 0, 0, 0);
            }
        }
        // K bias dropped (softmax-invariant)
        #pragma unroll
        for (int nt = 0; nt < 4; ++nt)
            #pragma unroll
            for (int mt = 0; mt < 2; ++mt) {
                uint2 d = make_uint2(pkbf(acc[mt][nt][0], acc[mt][nt][1]),
                                     pkbf(acc[mt][nt][2], acc[mt][nt][3]));
                *(uint2*)(scr + (nt * 16 + l16) * 36 + mt * 16 + 4 * g) = d;
            }
        #pragma unroll
        for (int nt = 0; nt < 4; ++nt)
            kf[nt] = *(const bf16x8*)(scr + (nt * 16 + l16) * 36 + lk);
    }

    // ---------- V-GEMM (normal: C = V, 64 tok x 32 d) ----------
    {
        f32x4 acc[4][2];
        #pragma unroll
        for (int rt = 0; rt < 4; ++rt) { acc[rt][0] = fz; acc[rt][1] = fz; }

        #pragma unroll 2
        for (int kb = 0; kb < 8; ++kb) {
            bf16x8 ax[4];
            #pragma unroll
            for (int rt = 0; rt < 4; ++rt)
                ax[rt] = *(const bf16x8*)(sX + (rt * 16 + l16) * 264 + kb * 32 + lk);
            #pragma unroll
            for (int ct = 0; ct < 2; ++ct) {
                bf16x8 bw = *(const bf16x8*)(w_qkv + (512 + h * 32 + ct * 16 + l16) * 256 + kb * 32 + lk);
                #pragma unroll
                for (int rt = 0; rt < 4; ++rt)
                    acc[rt][ct] = __builtin_amdgcn_mfma_f32_16x16x32_bf16(
                        ax[rt], bw, acc[rt][ct], 0, 0, 0);
            }
        }
        // V^T bounce: rows = kk*32 + d (disjoint halves, no WAR), cols = tok%32
        #pragma unroll
        for (int rt = 0; rt < 4; ++rt)
            #pragma unroll
            for (int ct = 0; ct < 2; ++ct) {
                uint2 d = make_uint2(pkbf(acc[rt][ct][0], acc[rt][ct][1]),
                                     pkbf(acc[rt][ct][2], acc[rt][ct][3]));
                *(uint2*)(scr + ((rt >> 1) * 32 + ct * 16 + l16) * 36 + (rt & 1) * 16 + 4 * g) = d;
            }
        #pragma unroll
        for (int dm = 0; dm < 2; ++dm)
            #pragma unroll
            for (int kk = 0; kk < 2; ++kk)
                vf[dm][kk] = *(const bf16x8*)(scr + (kk * 32 + dm * 16 + l16) * 36 + lk);
    }
    __syncthreads();   // all sX reads done; sO overlay now safe

    // ---------- attention (barrier-free, per-wave head), 2 query halves ----------
    const float* bp_h = bias_p + h * 4096;
    float4 bv0 = *(const float4*)(sbias + 512 + h * 32 + 4 * g);
    float4 bv1 = *(const float4*)(sbias + 512 + h * 32 + 16 + 4 * g);

    #pragma unroll
    for (int hf = 0; hf < 2; ++hf) {
        // S^T acc init from pre-masked bias (one dwordx4 per tile-row), 8 mfma
        f32x4 s[4][2];
        #pragma unroll
        for (int tr = 0; tr < 4; ++tr)
            #pragma unroll
            for (int tl = 0; tl < 2; ++tl) {
                const int i = (hf * 2 + tl) * 16 + l16;
                s[tr][tl] = *(const f32x4*)(bp_h + (tr * 4 + g) * 256 + i * 4);
            }
        #pragma unroll
        for (int tr = 0; tr < 4; ++tr)
            #pragma unroll
            for (int tl = 0; tl < 2; ++tl)
                s[tr][tl] = __builtin_amdgcn_mfma_f32_16x16x32_bf16(
                    kf[tr], qf[hf * 2 + tl], s[tr][tl], 0, 0, 0);

        // softmax without max-subtraction (|S| small by construction;
        // masked rows are -1e30 -> expf -> 0)
        float inv[2];
        #pragma unroll
        for (int tl = 0; tl < 2; ++tl) {
            float s4[4];
            #pragma unroll
            for (int tr = 0; tr < 4; ++tr) {
                float e0 = __expf(s[tr][tl][0]);
                float e1 = __expf(s[tr][tl][1]);
                float e2 = __expf(s[tr][tl][2]);
                float e3 = __expf(s[tr][tl][3]);
                s[tr][tl][0] = e0; s[tr][tl][1] = e1;
                s[tr][tl][2] = e2; s[tr][tl][3] = e3;
                s4[tr] = (e0 + e1) + (e2 + e3);
            }
            float sum = (s4[0] + s4[1]) + (s4[2] + s4[3]);
            sum += __shfl_xor(sum, 16);
            sum += __shfl_xor(sum, 32);
            inv[tl] = 1.0f / sum;
        }

        // P bounce: rows = kk*32 + i (disjoint halves), cols = j%32
        #pragma unroll
        for (int tr = 0; tr < 4; ++tr)
            #pragma unroll
            for (int tl = 0; tl < 2; ++tl) {
                uint2 d = make_uint2(pkbf(s[tr][tl][0], s[tr][tl][1]),
                                     pkbf(s[tr][tl][2], s[tr][tl][3]));
                *(uint2*)(scr + ((tr >> 1) * 32 + tl * 16 + l16) * 36 + (tr & 1) * 16 + 4 * g) = d;
            }
        bf16x8 pf[2][2];
        #pragma unroll
        for (int tl = 0; tl < 2; ++tl)
            #pragma unroll
            for (int kk = 0; kk < 2; ++kk)
                pf[tl][kk] = *(const bf16x8*)(scr + (kk * 32 + tl * 16 + l16) * 36 + lk);

        // O^T = V^T P  (unnormalized P; scale by inv afterwards)
        f32x4 o[2][2];
        #pragma unroll
        for (int dm = 0; dm < 2; ++dm) { o[dm][0] = fz; o[dm][1] = fz; }
        #pragma unroll
        for (int dm = 0; dm < 2; ++dm)
            #pragma unroll
            for (int tl = 0; tl < 2; ++tl)
                #pragma unroll
                for (int kk = 0; kk < 2; ++kk)
                    o[dm][tl] = __builtin_amdgcn_mfma_f32_16x16x32_bf16(
                        vf[dm][kk], pf[tl][kk], o[dm][tl], 0, 0, 0);

        // epilogue: *inv, +bv, pack, write O rows into sO
        #pragma unroll
        for (int dm = 0; dm < 2; ++dm) {
            const float4 bv = dm ? bv1 : bv0;
            #pragma unroll
            for (int tl = 0; tl < 2; ++tl) {
                const float iv = inv[tl];
                float r0 = o[dm][tl][0] * iv + bv.x;
                float r1 = o[dm][tl][1] * iv + bv.y;
                float r2 = o[dm][tl][2] * iv + bv.z;
                float r3 = o[dm][tl][3] * iv + bv.w;
                uint2 d = make_uint2(pkbf(r0, r1), pkbf(r2, r3));
                *(uint2*)(sO + ((hf * 2 + tl) * 16 + l16) * 264 + h * 32 + dm * 16 + 4 * g) = d;
            }
        }
    }
    __syncthreads();

    // ---------- proj GEMM (64x256, K=256), wave owns 32 cols ----------
    {
        f32x4 acc[4][2];
        #pragma unroll
        for (int rt = 0; rt < 4; ++rt) { acc[rt][0] = fz; acc[rt][1] = fz; }

        const int colbase = wv * 32;
        #pragma unroll 2
        for (int kb = 0; kb < 8; ++kb) {
            bf16x8 a[4];
            #pragma unroll
            for (int rt = 0; rt < 4; ++rt)
                a[rt] = *(const bf16x8*)(sO + (rt * 16 + l16) * 264 + kb * 32 + lk);
            #pragma unroll
            for (int c = 0; c < 2; ++c) {
                bf16x8 bw = *(const bf16x8*)(w_proj + (colbase + c * 16 + l16) * 256 + kb * 32 + lk);
                #pragma unroll
                for (int rt = 0; rt < 4; ++rt)
                    acc[rt][c] = __builtin_amdgcn_mfma_f32_16x16x32_bf16(
                        a[rt], bw, acc[rt][c], 0, 0, 0);
            }
        }
        float* ob = out + (size_t)b * (NTOK * 256);
        #pragma unroll
        for (int c = 0; c < 2; ++c) {
            const int col = colbase + c * 16 + l16;
            const float pb = proj_b[col];
            #pragma unroll
            for (int rt = 0; rt < 4; ++rt)
                #pragma unroll
                for (int r = 0; r < 4; ++r) {
                    const int row = rt * 16 + 4 * g + r;
                    if (row < NTOK) ob[row * 256 + col] = acc[rt][c][r] + pb;
                }
        }
    }
}

extern "C" void kernel_launch(void* const* d_in, const int* in_sizes, int n_in,
                              void* d_out, int out_size, void* d_ws, size_t ws_size,
                              hipStream_t stream) {
    const float* x          = (const float*)d_in[0];
    const float* qkv_w      = (const float*)d_in[1];
    const float* qkv_b      = (const float*)d_in[2];
    const float* proj_w     = (const float*)d_in[3];
    const float* proj_b     = (const float*)d_in[4];
    const float* bias_table = (const float*)d_in[5];

    unsigned short* w_qkv  = (unsigned short*)d_ws;      // 196608 bf16
    unsigned short* w_proj = w_qkv + 196608;             // 65536 bf16
    float*          bias_p = (float*)(w_proj + 65536);   // 32768 f32
    float*          sbias  = bias_p + 32768;             // 768 f32

    prep_kernel<<<288, 256, 0, stream>>>(qkv_w, proj_w, bias_table, qkv_b,
                                         w_qkv, w_proj, bias_p, sbias);

    const int SMEM = (64 * 264 + 8 * 64 * 36) * 2;       // 70656 B
    hipFuncSetAttribute(reinterpret_cast<const void*>(wattn_kernel),
                        hipFuncAttributeMaxDynamicSharedMemorySize, SMEM);

    wattn_kernel<<<8192, 512, SMEM, stream>>>(x, w_qkv, w_proj, bias_p, sbias,
                                              proj_b, (float*)d_out);
}

// Round 8
// 645.113 us; speedup vs baseline: 1.2939x; 1.0026x over previous
//
#include <hip/hip_runtime.h>
#include <hip/hip_bf16.h>
#include <stdint.h>

#define NTOK 49
#define SCALE 0.17677669529663687f

typedef __attribute__((ext_vector_type(8))) short bf16x8;
typedef __attribute__((ext_vector_type(4))) float f32x4;

__device__ __forceinline__ unsigned short f2bf(float f) {
    union { float f; unsigned int u; } v; v.f = f;
    unsigned int r = v.u + 0x7FFFu + ((v.u >> 16) & 1u);
    return (unsigned short)(r >> 16);
}

__device__ __forceinline__ uint32_t pkbf(float lo, float hi) {
    __hip_bfloat162 h = __float22bfloat162_rn(float2{lo, hi});
    union { __hip_bfloat162 h; uint32_t u; } c; c.h = h;
    return c.u;
}

// ---- prep: bf16 weights (Q rows pre-scaled), bias in [h][j/4][i][j%4]
// ---- layout (one dwordx4 per S-tile-row init), scaled qkv bias copy ----
__global__ void prep_kernel(const float* __restrict__ qkv_w,
                            const float* __restrict__ proj_w,
                            const float* __restrict__ bias_table,
                            const float* __restrict__ qkv_b,
                            unsigned short* __restrict__ w_qkv,
                            unsigned short* __restrict__ w_proj,
                            float* __restrict__ bias_p,
                            float* __restrict__ sbias) {
    const int total = 196608 + 65536 + 32768 + 768;
    for (int i = blockIdx.x * blockDim.x + threadIdx.x; i < total;
         i += gridDim.x * blockDim.x) {
        if (i < 196608) {
            float s = (i < 65536) ? SCALE : 1.0f;   // Q rows pre-scaled
            w_qkv[i] = f2bf(qkv_w[i] * s);
        } else if (i < 262144) {
            w_proj[i - 196608] = f2bf(proj_w[i - 196608]);
        } else if (i < 294912) {
            int idx = i - 262144;
            int hh = idx >> 12;             // head
            int j  = (idx >> 6) & 63;       // key token
            int ii = idx & 63;              // query token
            float v;
            if (j >= NTOK)       v = -1e30f;            // mask padded keys
            else if (ii >= NTOK) v = 0.0f;              // garbage queries: finite
            else {
                int rel = (ii / 7 - j / 7 + 6) * 13 + (ii % 7 - j % 7 + 6);
                v = bias_table[rel * 8 + hh];
            }
            // layout: [h][j>>2][ii][j&3]  -> float4 over r=j&3
            bias_p[hh * 4096 + (j >> 2) * 256 + ii * 4 + (j & 3)] = v;
        } else {
            int r = i - 294912;
            sbias[r] = qkv_b[r] * (r < 256 ? SCALE : 1.0f);
        }
    }
}

// ---- fused window attention: one window/block, 8 waves, 1 head/wave ----
// LDS: sX [64][264] bf16 (33792 B, O written back post-attention) +
// per-wave scratch [64][36] bf16 (4608 B x 8). Total 70656 B -> 2 blocks/CU.
// Barrier plan: stage | bar | {Q,K,V-GEMM, attention: barrier-free,
// per-wave independent -> waves desync, stalls decorrelate} | bar |
// O regs->sX | bar | proj. O held in 16 packed-bf16 regs through attention.
__global__ __launch_bounds__(512, 4) void wattn_kernel(
    const float* __restrict__ x,
    const unsigned short* __restrict__ w_qkv,
    const unsigned short* __restrict__ w_proj,
    const float* __restrict__ bias_p,
    const float* __restrict__ sbias,
    const float* __restrict__ proj_b,
    float* __restrict__ out)
{
    extern __shared__ char smem[];
    unsigned short* sX = (unsigned short*)smem;       // 64*264 elems
    unsigned short* scrBase = sX + 64 * 264;

    const int tid  = threadIdx.x;
    const int wv   = tid >> 6;
    const int lane = tid & 63;
    const int l16  = lane & 15;
    const int g    = lane >> 4;
    const int lk   = g * 8;

    unsigned short* scr = scrBase + wv * (64 * 36);   // [64][36] per wave
    const int b = blockIdx.x;
    const int h = wv;
    const f32x4 fz = {0.f, 0.f, 0.f, 0.f};

    // ---------- stage x -> LDS bf16, zero pad rows ----------
    const float* xb = x + (size_t)b * (NTOK * 256);
    for (int it = tid * 4; it < NTOK * 256; it += 512 * 4) {
        float4 v = *(const float4*)(xb + it);
        int r = it >> 8, c = it & 255;
        uint2 u = make_uint2(pkbf(v.x, v.y), pkbf(v.z, v.w));
        *(uint2*)(sX + r * 264 + c) = u;
    }
    for (int it = tid * 4; it < 15 * 256; it += 512 * 4) {
        int r = 49 + (it >> 8), c = it & 255;
        *(uint2*)(sX + r * 264 + c) = make_uint2(0, 0);
    }
    __syncthreads();

    bf16x8 qf[4], kf[4], vf[2][2];

    // ---------- Q-GEMM (transposed: C = Q^T tiles, 32 feat x 64 tok) ----------
    {
        f32x4 acc[2][4];
        #pragma unroll
        for (int mt = 0; mt < 2; ++mt)
            #pragma unroll
            for (int nt = 0; nt < 4; ++nt) acc[mt][nt] = fz;

        #pragma unroll 2
        for (int kb = 0; kb < 8; ++kb) {
            bf16x8 bx[4];
            #pragma unroll
            for (int nt = 0; nt < 4; ++nt)
                bx[nt] = *(const bf16x8*)(sX + (nt * 16 + l16) * 264 + kb * 32 + lk);
            #pragma unroll
            for (int mt = 0; mt < 2; ++mt) {
                bf16x8 aw = *(const bf16x8*)(w_qkv + (h * 32 + mt * 16 + l16) * 256 + kb * 32 + lk);
                #pragma unroll
                for (int nt = 0; nt < 4; ++nt)
                    acc[mt][nt] = __builtin_amdgcn_mfma_f32_16x16x32_bf16(
                        aw, bx[nt], acc[mt][nt], 0, 0, 0);
            }
        }
        // Q bias (pre-scaled)
        float4 bq0 = *(const float4*)(sbias + h * 32 + 4 * g);
        float4 bq1 = *(const float4*)(sbias + h * 32 + 16 + 4 * g);
        #pragma unroll
        for (int nt = 0; nt < 4; ++nt) {
            acc[0][nt][0] += bq0.x; acc[0][nt][1] += bq0.y;
            acc[0][nt][2] += bq0.z; acc[0][nt][3] += bq0.w;
            acc[1][nt][0] += bq1.x; acc[1][nt][1] += bq1.y;
            acc[1][nt][2] += bq1.z; acc[1][nt][3] += bq1.w;
        }
        // bounce: [token 0..63][feat 0..31] in scr[64][36], single round
        #pragma unroll
        for (int nt = 0; nt < 4; ++nt)
            #pragma unroll
            for (int mt = 0; mt < 2; ++mt) {
                uint2 d = make_uint2(pkbf(acc[mt][nt][0], acc[mt][nt][1]),
                                     pkbf(acc[mt][nt][2], acc[mt][nt][3]));
                *(uint2*)(scr + (nt * 16 + l16) * 36 + mt * 16 + 4 * g) = d;
            }
        #pragma unroll
        for (int nt = 0; nt < 4; ++nt)
            qf[nt] = *(const bf16x8*)(scr + (nt * 16 + l16) * 36 + lk);
    }

    // ---------- K-GEMM (same shape; WAR vs Q reads separated by GEMM) ----------
    {
        f32x4 acc[2][4];
        #pragma unroll
        for (int mt = 0; mt < 2; ++mt)
            #pragma unroll
            for (int nt = 0; nt < 4; ++nt) acc[mt][nt] = fz;

        #pragma unroll 2
        for (int kb = 0; kb < 8; ++kb) {
            bf16x8 bx[4];
            #pragma unroll
            for (int nt = 0; nt < 4; ++nt)
                bx[nt] = *(const bf16x8*)(sX + (nt * 16 + l16) * 264 + kb * 32 + lk);
            #pragma unroll
            for (int mt = 0; mt < 2; ++mt) {
                bf16x8 aw = *(const bf16x8*)(w_qkv + (256 + h * 32 + mt * 16 + l16) * 256 + kb * 32 + lk);
                #pragma unroll
                for (int nt = 0; nt < 4; ++nt)
                    acc[mt][nt] = __builtin_amdgcn_mfma_f32_16x16x32_bf16(
                        aw, bx[nt], acc[mt][nt], 0, 0, 0);
            }
        }
        // K bias dropped (softmax-invariant)
        #pragma unroll
        for (int nt = 0; nt < 4; ++nt)
            #pragma unroll
            for (int mt = 0; mt < 2; ++mt) {
                uint2 d = make_uint2(pkbf(acc[mt][nt][0], acc[mt][nt][1]),
                                     pkbf(acc[mt][nt][2], acc[mt][nt][3]));
                *(uint2*)(scr + (nt * 16 + l16) * 36 + mt * 16 + 4 * g) = d;
            }
        #pragma unroll
        for (int nt = 0; nt < 4; ++nt)
            kf[nt] = *(const bf16x8*)(scr + (nt * 16 + l16) * 36 + lk);
    }

    // ---------- V-GEMM (normal: C = V, 64 tok x 32 d) ----------
    {
        f32x4 acc[4][2];
        #pragma unroll
        for (int rt = 0; rt < 4; ++rt) { acc[rt][0] = fz; acc[rt][1] = fz; }

        #pragma unroll 2
        for (int kb = 0; kb < 8; ++kb) {
            bf16x8 ax[4];
            #pragma unroll
            for (int rt = 0; rt < 4; ++rt)
                ax[rt] = *(const bf16x8*)(sX + (rt * 16 + l16) * 264 + kb * 32 + lk);
            #pragma unroll
            for (int ct = 0; ct < 2; ++ct) {
                bf16x8 bw = *(const bf16x8*)(w_qkv + (512 + h * 32 + ct * 16 + l16) * 256 + kb * 32 + lk);
                #pragma unroll
                for (int rt = 0; rt < 4; ++rt)
                    acc[rt][ct] = __builtin_amdgcn_mfma_f32_16x16x32_bf16(
                        ax[rt], bw, acc[rt][ct], 0, 0, 0);
            }
        }
        // V^T bounce: rows = kk*32 + d (disjoint halves, no WAR), cols = tok%32
        #pragma unroll
        for (int rt = 0; rt < 4; ++rt)
            #pragma unroll
            for (int ct = 0; ct < 2; ++ct) {
                uint2 d = make_uint2(pkbf(acc[rt][ct][0], acc[rt][ct][1]),
                                     pkbf(acc[rt][ct][2], acc[rt][ct][3]));
                *(uint2*)(scr + ((rt >> 1) * 32 + ct * 16 + l16) * 36 + (rt & 1) * 16 + 4 * g) = d;
            }
        #pragma unroll
        for (int dm = 0; dm < 2; ++dm)
            #pragma unroll
            for (int kk = 0; kk < 2; ++kk)
                vf[dm][kk] = *(const bf16x8*)(scr + (kk * 32 + dm * 16 + l16) * 36 + lk);
    }
    // NO barrier: attention below touches only per-wave scr + global bias.
    // Waves proceed independently -> stalls decorrelate across the block.

    // ---------- attention (barrier-free, per-wave head), 2 query halves ----------
    const float* bp_h = bias_p + h * 4096;
    float4 bv0 = *(const float4*)(sbias + 512 + h * 32 + 4 * g);
    float4 bv1 = *(const float4*)(sbias + 512 + h * 32 + 16 + 4 * g);

    uint2 o_st[2][2][2];   // [hf][dm][tl] packed bf16 O, written to sX later

    #pragma unroll
    for (int hf = 0; hf < 2; ++hf) {
        // S^T acc init from pre-masked bias (one dwordx4 per tile-row), 8 mfma
        f32x4 s[4][2];
        #pragma unroll
        for (int tr = 0; tr < 4; ++tr)
            #pragma unroll
            for (int tl = 0; tl < 2; ++tl) {
                const int i = (hf * 2 + tl) * 16 + l16;
                s[tr][tl] = *(const f32x4*)(bp_h + (tr * 4 + g) * 256 + i * 4);
            }
        __builtin_amdgcn_s_setprio(1);
        #pragma unroll
        for (int tr = 0; tr < 4; ++tr)
            #pragma unroll
            for (int tl = 0; tl < 2; ++tl)
                s[tr][tl] = __builtin_amdgcn_mfma_f32_16x16x32_bf16(
                    kf[tr], qf[hf * 2 + tl], s[tr][tl], 0, 0, 0);
        __builtin_amdgcn_s_setprio(0);

        // softmax without max-subtraction (|S| small by construction;
        // masked rows are -1e30 -> expf -> 0)
        float inv[2];
        #pragma unroll
        for (int tl = 0; tl < 2; ++tl) {
            float s4[4];
            #pragma unroll
            for (int tr = 0; tr < 4; ++tr) {
                float e0 = __expf(s[tr][tl][0]);
                float e1 = __expf(s[tr][tl][1]);
                float e2 = __expf(s[tr][tl][2]);
                float e3 = __expf(s[tr][tl][3]);
                s[tr][tl][0] = e0; s[tr][tl][1] = e1;
                s[tr][tl][2] = e2; s[tr][tl][3] = e3;
                s4[tr] = (e0 + e1) + (e2 + e3);
            }
            float sum = (s4[0] + s4[1]) + (s4[2] + s4[3]);
            sum += __shfl_xor(sum, 16);
            sum += __shfl_xor(sum, 32);
            inv[tl] = 1.0f / sum;
        }

        // P bounce: rows = kk*32 + i (disjoint halves), cols = j%32
        #pragma unroll
        for (int tr = 0; tr < 4; ++tr)
            #pragma unroll
            for (int tl = 0; tl < 2; ++tl) {
                uint2 d = make_uint2(pkbf(s[tr][tl][0], s[tr][tl][1]),
                                     pkbf(s[tr][tl][2], s[tr][tl][3]));
                *(uint2*)(scr + ((tr >> 1) * 32 + tl * 16 + l16) * 36 + (tr & 1) * 16 + 4 * g) = d;
            }
        bf16x8 pf[2][2];
        #pragma unroll
        for (int tl = 0; tl < 2; ++tl)
            #pragma unroll
            for (int kk = 0; kk < 2; ++kk)
                pf[tl][kk] = *(const bf16x8*)(scr + (kk * 32 + tl * 16 + l16) * 36 + lk);

        // O^T = V^T P  (unnormalized P; scale by inv afterwards)
        f32x4 o[2][2];
        #pragma unroll
        for (int dm = 0; dm < 2; ++dm) { o[dm][0] = fz; o[dm][1] = fz; }
        __builtin_amdgcn_s_setprio(1);
        #pragma unroll
        for (int dm = 0; dm < 2; ++dm)
            #pragma unroll
            for (int tl = 0; tl < 2; ++tl)
                #pragma unroll
                for (int kk = 0; kk < 2; ++kk)
                    o[dm][tl] = __builtin_amdgcn_mfma_f32_16x16x32_bf16(
                        vf[dm][kk], pf[tl][kk], o[dm][tl], 0, 0, 0);
        __builtin_amdgcn_s_setprio(0);

        // epilogue: *inv, +bv, pack into registers (written to sX post-barrier)
        #pragma unroll
        for (int dm = 0; dm < 2; ++dm) {
            const float4 bv = dm ? bv1 : bv0;
            #pragma unroll
            for (int tl = 0; tl < 2; ++tl) {
                const float iv = inv[tl];
                float r0 = o[dm][tl][0] * iv + bv.x;
                float r1 = o[dm][tl][1] * iv + bv.y;
                float r2 = o[dm][tl][2] * iv + bv.z;
                float r3 = o[dm][tl][3] * iv + bv.w;
                o_st[hf][dm][tl] = make_uint2(pkbf(r0, r1), pkbf(r2, r3));
            }
        }
    }

    __syncthreads();   // all waves done reading sX (V-GEMM) -> overlay safe

    // ---------- write O regs -> sX ----------
    #pragma unroll
    for (int hf = 0; hf < 2; ++hf)
        #pragma unroll
        for (int dm = 0; dm < 2; ++dm)
            #pragma unroll
            for (int tl = 0; tl < 2; ++tl)
                *(uint2*)(sX + ((hf * 2 + tl) * 16 + l16) * 264 + h * 32 + dm * 16 + 4 * g)
                    = o_st[hf][dm][tl];
    __syncthreads();

    // ---------- proj GEMM (64x256, K=256), wave owns 32 cols ----------
    {
        f32x4 acc[4][2];
        #pragma unroll
        for (int rt = 0; rt < 4; ++rt) { acc[rt][0] = fz; acc[rt][1] = fz; }

        const int colbase = wv * 32;
        #pragma unroll 2
        for (int kb = 0; kb < 8; ++kb) {
            bf16x8 a[4];
            #pragma unroll
            for (int rt = 0; rt < 4; ++rt)
                a[rt] = *(const bf16x8*)(sX + (rt * 16 + l16) * 264 + kb * 32 + lk);
            #pragma unroll
            for (int c = 0; c < 2; ++c) {
                bf16x8 bw = *(const bf16x8*)(w_proj + (colbase + c * 16 + l16) * 256 + kb * 32 + lk);
                #pragma unroll
                for (int rt = 0; rt < 4; ++rt)
                    acc[rt][c] = __builtin_amdgcn_mfma_f32_16x16x32_bf16(
                        a[rt], bw, acc[rt][c], 0, 0, 0);
            }
        }
        float* ob = out + (size_t)b * (NTOK * 256);
        #pragma unroll
        for (int c = 0; c < 2; ++c) {
            const int col = colbase + c * 16 + l16;
            const float pb = proj_b[col];
            #pragma unroll
            for (int rt = 0; rt < 4; ++rt)
                #pragma unroll
                for (int r = 0; r < 4; ++r) {
                    const int row = rt * 16 + 4 * g + r;
                    if (row < NTOK) ob[row * 256 + col] = acc[rt][c][r] + pb;
                }
        }
    }
}

extern "C" void kernel_launch(void* const* d_in, const int* in_sizes, int n_in,
                              void* d_out, int out_size, void* d_ws, size_t ws_size,
                              hipStream_t stream) {
    const float* x          = (const float*)d_in[0];
    const float* qkv_w      = (const float*)d_in[1];
    const float* qkv_b      = (const float*)d_in[2];
    const float* proj_w     = (const float*)d_in[3];
    const float* proj_b     = (const float*)d_in[4];
    const float* bias_table = (const float*)d_in[5];

    unsigned short* w_qkv  = (unsigned short*)d_ws;      // 196608 bf16
    unsigned short* w_proj = w_qkv + 196608;             // 65536 bf16
    float*          bias_p = (float*)(w_proj + 65536);   // 32768 f32
    float*          sbias  = bias_p + 32768;             // 768 f32

    prep_kernel<<<288, 256, 0, stream>>>(qkv_w, proj_w, bias_table, qkv_b,
                                         w_qkv, w_proj, bias_p, sbias);

    const int SMEM = (64 * 264 + 8 * 64 * 36) * 2;       // 70656 B
    hipFuncSetAttribute(reinterpret_cast<const void*>(wattn_kernel),
                        hipFuncAttributeMaxDynamicSharedMemorySize, SMEM);

    wattn_kernel<<<8192, 512, SMEM, stream>>>(x, w_qkv, w_proj, bias_p, sbias,
                                              proj_b, (float*)d_out);
}

// Round 9
// 604.972 us; speedup vs baseline: 1.3798x; 1.0664x over previous
//
#include <hip/hip_runtime.h>
#include <hip/hip_bf16.h>
#include <stdint.h>

#define NTOK 49
#define SCALE 0.17677669529663687f
#define LOG2E 1.4426950408889634f

typedef __attribute__((ext_vector_type(8))) short bf16x8;
typedef __attribute__((ext_vector_type(4))) float f32x4;

__device__ __forceinline__ unsigned short f2bf(float f) {
    union { float f; unsigned int u; } v; v.f = f;
    unsigned int r = v.u + 0x7FFFu + ((v.u >> 16) & 1u);
    return (unsigned short)(r >> 16);
}

__device__ __forceinline__ uint32_t pkbf(float lo, float hi) {
    __hip_bfloat162 h = __float22bfloat162_rn(float2{lo, hi});
    union { __hip_bfloat162 h; uint32_t u; } c; c.h = h;
    return c.u;
}

// ---- prep: bf16 weights (Q rows pre-scaled by SCALE*LOG2E for exp2 softmax),
// ---- bias in [h][j/4][i][j%4] layout scaled by LOG2E, scaled qkv bias copy ----
__global__ void prep_kernel(const float* __restrict__ qkv_w,
                            const float* __restrict__ proj_w,
                            const float* __restrict__ bias_table,
                            const float* __restrict__ qkv_b,
                            unsigned short* __restrict__ w_qkv,
                            unsigned short* __restrict__ w_proj,
                            float* __restrict__ bias_p,
                            float* __restrict__ sbias) {
    const int total = 196608 + 65536 + 32768 + 768;
    for (int i = blockIdx.x * blockDim.x + threadIdx.x; i < total;
         i += gridDim.x * blockDim.x) {
        if (i < 196608) {
            float s = (i < 65536) ? SCALE * LOG2E : 1.0f;   // Q rows pre-scaled
            w_qkv[i] = f2bf(qkv_w[i] * s);
        } else if (i < 262144) {
            w_proj[i - 196608] = f2bf(proj_w[i - 196608]);
        } else if (i < 294912) {
            int idx = i - 262144;
            int hh = idx >> 12;             // head
            int j  = (idx >> 6) & 63;       // key token
            int ii = idx & 63;              // query token
            float v;
            if (j >= NTOK)       v = -1e30f;            // mask padded keys
            else if (ii >= NTOK) v = 0.0f;              // garbage queries: finite
            else {
                int rel = (ii / 7 - j / 7 + 6) * 13 + (ii % 7 - j % 7 + 6);
                v = bias_table[rel * 8 + hh];
            }
            // layout: [h][j>>2][ii][j&3] -> float4 over r=j&3; LOG2E folded
            bias_p[hh * 4096 + (j >> 2) * 256 + ii * 4 + (j & 3)] = v * LOG2E;
        } else {
            int r = i - 294912;
            sbias[r] = qkv_b[r] * (r < 256 ? SCALE * LOG2E : 1.0f);
        }
    }
}

// ---- fused window attention: one window/block, 8 waves, 1 head/wave ----
// LDS: sX [64][264] bf16 (33792 B, O written back post-attention) +
// per-wave scratch [64][36] bf16 (4608 B x 8). Total 70656 B.
// Occupancy is REG-limited: 64 VGPR + 64 AGPR = 128 -> 16 waves/CU max.
// So optimize per-wave issue: merged Q+K GEMM (acc[4][4]=64 AGPR, unroll 2
// to avoid R5's hoist-spills), exp2 softmax (LOG2E pre-folded), static loops.
__global__ __launch_bounds__(512, 4) void wattn_kernel(
    const float* __restrict__ x,
    const unsigned short* __restrict__ w_qkv,
    const unsigned short* __restrict__ w_proj,
    const float* __restrict__ bias_p,
    const float* __restrict__ sbias,
    const float* __restrict__ proj_b,
    float* __restrict__ out)
{
    extern __shared__ char smem[];
    unsigned short* sX = (unsigned short*)smem;       // 64*264 elems
    unsigned short* scrBase = sX + 64 * 264;

    const int tid  = threadIdx.x;
    const int wv   = tid >> 6;
    const int lane = tid & 63;
    const int l16  = lane & 15;
    const int g    = lane >> 4;
    const int lk   = g * 8;

    unsigned short* scr = scrBase + wv * (64 * 36);   // [64][36] per wave
    const int b = blockIdx.x;
    const int h = wv;
    const f32x4 fz = {0.f, 0.f, 0.f, 0.f};

    // ---------- stage x -> LDS bf16 (static trip counts), zero pad rows ----------
    const float* xb = x + (size_t)b * (NTOK * 256);
    #pragma unroll
    for (int it = 0; it < 6; ++it) {
        const int idx = tid * 4 + it * 2048;          // < 12288 always valid
        float4 v = *(const float4*)(xb + idx);
        int r = idx >> 8, c = idx & 255;
        *(uint2*)(sX + r * 264 + c) = make_uint2(pkbf(v.x, v.y), pkbf(v.z, v.w));
    }
    if (tid < 64) {                                    // tail: 12288..12543
        const int idx = tid * 4 + 12288;
        float4 v = *(const float4*)(xb + idx);
        int r = idx >> 8, c = idx & 255;
        *(uint2*)(sX + r * 264 + c) = make_uint2(pkbf(v.x, v.y), pkbf(v.z, v.w));
    }
    {                                                  // zero rows 49..63 (3840 elems)
        const int i0 = tid * 4;
        *(uint2*)(sX + (49 + (i0 >> 8)) * 264 + (i0 & 255)) = make_uint2(0, 0);
        const int i1 = i0 + 2048;
        if (i1 < 3840)
            *(uint2*)(sX + (49 + (i1 >> 8)) * 264 + (i1 & 255)) = make_uint2(0, 0);
    }
    __syncthreads();

    bf16x8 qf[4], kf[4], vf[2][2];

    // ---------- merged Q+K GEMM (C = [Q;K]^T, 64 feat x 64 tok) ----------
    // acc[4][4] = 64 AGPR; unroll 2 caps hoisted loads (R7 lesson: no spills)
    {
        f32x4 acc[4][4];
        #pragma unroll
        for (int mt = 0; mt < 4; ++mt)
            #pragma unroll
            for (int nt = 0; nt < 4; ++nt) acc[mt][nt] = fz;

        #pragma unroll 2
        for (int kb = 0; kb < 8; ++kb) {
            bf16x8 bx[4];
            #pragma unroll
            for (int nt = 0; nt < 4; ++nt)
                bx[nt] = *(const bf16x8*)(sX + (nt * 16 + l16) * 264 + kb * 32 + lk);
            #pragma unroll
            for (int mt = 0; mt < 4; ++mt) {
                const int wrow = (mt < 2) ? (h * 32 + mt * 16 + l16)
                                          : (256 + h * 32 + (mt - 2) * 16 + l16);
                bf16x8 aw = *(const bf16x8*)(w_qkv + wrow * 256 + kb * 32 + lk);
                #pragma unroll
                for (int nt = 0; nt < 4; ++nt)
                    acc[mt][nt] = __builtin_amdgcn_mfma_f32_16x16x32_bf16(
                        aw, bx[nt], acc[mt][nt], 0, 0, 0);
            }
        }
        // Q bias (pre-scaled); K bias dropped (softmax-invariant)
        float4 bq0 = *(const float4*)(sbias + h * 32 + 4 * g);
        float4 bq1 = *(const float4*)(sbias + h * 32 + 16 + 4 * g);
        #pragma unroll
        for (int nt = 0; nt < 4; ++nt) {
            acc[0][nt][0] += bq0.x; acc[0][nt][1] += bq0.y;
            acc[0][nt][2] += bq0.z; acc[0][nt][3] += bq0.w;
            acc[1][nt][0] += bq1.x; acc[1][nt][1] += bq1.y;
            acc[1][nt][2] += bq1.z; acc[1][nt][3] += bq1.w;
        }
        // Q bounce (mt 0-1): [token][feat] in scr[64][36]
        #pragma unroll
        for (int nt = 0; nt < 4; ++nt)
            #pragma unroll
            for (int mt = 0; mt < 2; ++mt) {
                uint2 d = make_uint2(pkbf(acc[mt][nt][0], acc[mt][nt][1]),
                                     pkbf(acc[mt][nt][2], acc[mt][nt][3]));
                *(uint2*)(scr + (nt * 16 + l16) * 36 + mt * 16 + 4 * g) = d;
            }
        #pragma unroll
        for (int nt = 0; nt < 4; ++nt)
            qf[nt] = *(const bf16x8*)(scr + (nt * 16 + l16) * 36 + lk);
        // K bounce (mt 2-3): same slots; DS in-wave ordering keeps qf reads safe
        #pragma unroll
        for (int nt = 0; nt < 4; ++nt)
            #pragma unroll
            for (int mt = 2; mt < 4; ++mt) {
                uint2 d = make_uint2(pkbf(acc[mt][nt][0], acc[mt][nt][1]),
                                     pkbf(acc[mt][nt][2], acc[mt][nt][3]));
                *(uint2*)(scr + (nt * 16 + l16) * 36 + (mt - 2) * 16 + 4 * g) = d;
            }
        #pragma unroll
        for (int nt = 0; nt < 4; ++nt)
            kf[nt] = *(const bf16x8*)(scr + (nt * 16 + l16) * 36 + lk);
    }

    // ---------- V-GEMM (normal: C = V, 64 tok x 32 d) ----------
    {
        f32x4 acc[4][2];
        #pragma unroll
        for (int rt = 0; rt < 4; ++rt) { acc[rt][0] = fz; acc[rt][1] = fz; }

        #pragma unroll 2
        for (int kb = 0; kb < 8; ++kb) {
            bf16x8 ax[4];
            #pragma unroll
            for (int rt = 0; rt < 4; ++rt)
                ax[rt] = *(const bf16x8*)(sX + (rt * 16 + l16) * 264 + kb * 32 + lk);
            #pragma unroll
            for (int ct = 0; ct < 2; ++ct) {
                bf16x8 bw = *(const bf16x8*)(w_qkv + (512 + h * 32 + ct * 16 + l16) * 256 + kb * 32 + lk);
                #pragma unroll
                for (int rt = 0; rt < 4; ++rt)
                    acc[rt][ct] = __builtin_amdgcn_mfma_f32_16x16x32_bf16(
                        ax[rt], bw, acc[rt][ct], 0, 0, 0);
            }
        }
        // V^T bounce: rows = kk*32 + d (disjoint halves), cols = tok%32
        #pragma unroll
        for (int rt = 0; rt < 4; ++rt)
            #pragma unroll
            for (int ct = 0; ct < 2; ++ct) {
                uint2 d = make_uint2(pkbf(acc[rt][ct][0], acc[rt][ct][1]),
                                     pkbf(acc[rt][ct][2], acc[rt][ct][3]));
                *(uint2*)(scr + ((rt >> 1) * 32 + ct * 16 + l16) * 36 + (rt & 1) * 16 + 4 * g) = d;
            }
        #pragma unroll
        for (int dm = 0; dm < 2; ++dm)
            #pragma unroll
            for (int kk = 0; kk < 2; ++kk)
                vf[dm][kk] = *(const bf16x8*)(scr + (kk * 32 + dm * 16 + l16) * 36 + lk);
    }
    // NO barrier: attention touches only per-wave scr + global bias.

    // ---------- attention (barrier-free, per-wave head), 2 query halves ----------
    const float* bp_h = bias_p + h * 4096;
    float4 bv0 = *(const float4*)(sbias + 512 + h * 32 + 4 * g);
    float4 bv1 = *(const float4*)(sbias + 512 + h * 32 + 16 + 4 * g);

    uint2 o_st[2][2][2];   // [hf][dm][tl] packed bf16 O, written to sX later

    #pragma unroll
    for (int hf = 0; hf < 2; ++hf) {
        // S^T acc init from pre-masked bias (one dwordx4 per tile-row), 8 mfma
        f32x4 s[4][2];
        #pragma unroll
        for (int tr = 0; tr < 4; ++tr)
            #pragma unroll
            for (int tl = 0; tl < 2; ++tl) {
                const int i = (hf * 2 + tl) * 16 + l16;
                s[tr][tl] = *(const f32x4*)(bp_h + (tr * 4 + g) * 256 + i * 4);
            }
        __builtin_amdgcn_s_setprio(1);
        #pragma unroll
        for (int tr = 0; tr < 4; ++tr)
            #pragma unroll
            for (int tl = 0; tl < 2; ++tl)
                s[tr][tl] = __builtin_amdgcn_mfma_f32_16x16x32_bf16(
                    kf[tr], qf[hf * 2 + tl], s[tr][tl], 0, 0, 0);
        __builtin_amdgcn_s_setprio(0);

        // softmax in base-2 (LOG2E pre-folded into W_q, bq, bias) —
        // raw v_exp_f32, no max-subtraction (|S| small; masked -> 0)
        float inv[2];
        #pragma unroll
        for (int tl = 0; tl < 2; ++tl) {
            float s4[4];
            #pragma unroll
            for (int tr = 0; tr < 4; ++tr) {
                float e0 = __builtin_amdgcn_exp2f(s[tr][tl][0]);
                float e1 = __builtin_amdgcn_exp2f(s[tr][tl][1]);
                float e2 = __builtin_amdgcn_exp2f(s[tr][tl][2]);
                float e3 = __builtin_amdgcn_exp2f(s[tr][tl][3]);
                s[tr][tl][0] = e0; s[tr][tl][1] = e1;
                s[tr][tl][2] = e2; s[tr][tl][3] = e3;
                s4[tr] = (e0 + e1) + (e2 + e3);
            }
            float sum = (s4[0] + s4[1]) + (s4[2] + s4[3]);
            sum += __shfl_xor(sum, 16);
            sum += __shfl_xor(sum, 32);
            inv[tl] = 1.0f / sum;
        }

        // P bounce: rows = kk*32 + i (disjoint halves), cols = j%32
        #pragma unroll
        for (int tr = 0; tr < 4; ++tr)
            #pragma unroll
            for (int tl = 0; tl < 2; ++tl) {
                uint2 d = make_uint2(pkbf(s[tr][tl][0], s[tr][tl][1]),
                                     pkbf(s[tr][tl][2], s[tr][tl][3]));
                *(uint2*)(scr + ((tr >> 1) * 32 + tl * 16 + l16) * 36 + (tr & 1) * 16 + 4 * g) = d;
            }
        bf16x8 pf[2][2];
        #pragma unroll
        for (int tl = 0; tl < 2; ++tl)
            #pragma unroll
            for (int kk = 0; kk < 2; ++kk)
                pf[tl][kk] = *(const bf16x8*)(scr + (kk * 32 + tl * 16 + l16) * 36 + lk);

        // O^T = V^T P  (unnormalized P; scale by inv afterwards)
        f32x4 o[2][2];
        #pragma unroll
        for (int dm = 0; dm < 2; ++dm) { o[dm][0] = fz; o[dm][1] = fz; }
        __builtin_amdgcn_s_setprio(1);
        #pragma unroll
        for (int dm = 0; dm < 2; ++dm)
            #pragma unroll
            for (int tl = 0; tl < 2; ++tl)
                #pragma unroll
                for (int kk = 0; kk < 2; ++kk)
                    o[dm][tl] = __builtin_amdgcn_mfma_f32_16x16x32_bf16(
                        vf[dm][kk], pf[tl][kk], o[dm][tl], 0, 0, 0);
        __builtin_amdgcn_s_setprio(0);

        // epilogue: *inv, +bv, pack into registers (written to sX post-barrier)
        #pragma unroll
        for (int dm = 0; dm < 2; ++dm) {
            const float4 bv = dm ? bv1 : bv0;
            #pragma unroll
            for (int tl = 0; tl < 2; ++tl) {
                const float iv = inv[tl];
                float r0 = o[dm][tl][0] * iv + bv.x;
                float r1 = o[dm][tl][1] * iv + bv.y;
                float r2 = o[dm][tl][2] * iv + bv.z;
                float r3 = o[dm][tl][3] * iv + bv.w;
                o_st[hf][dm][tl] = make_uint2(pkbf(r0, r1), pkbf(r2, r3));
            }
        }
    }

    __syncthreads();   // all waves done reading sX (V-GEMM) -> overlay safe

    // ---------- write O regs -> sX ----------
    #pragma unroll
    for (int hf = 0; hf < 2; ++hf)
        #pragma unroll
        for (int dm = 0; dm < 2; ++dm)
            #pragma unroll
            for (int tl = 0; tl < 2; ++tl)
                *(uint2*)(sX + ((hf * 2 + tl) * 16 + l16) * 264 + h * 32 + dm * 16 + 4 * g)
                    = o_st[hf][dm][tl];
    __syncthreads();

    // ---------- proj GEMM (64x256, K=256), wave owns 32 cols ----------
    {
        f32x4 acc[4][2];
        #pragma unroll
        for (int rt = 0; rt < 4; ++rt) { acc[rt][0] = fz; acc[rt][1] = fz; }

        const int colbase = wv * 32;
        #pragma unroll 2
        for (int kb = 0; kb < 8; ++kb) {
            bf16x8 a[4];
            #pragma unroll
            for (int rt = 0; rt < 4; ++rt)
                a[rt] = *(const bf16x8*)(sX + (rt * 16 + l16) * 264 + kb * 32 + lk);
            #pragma unroll
            for (int c = 0; c < 2; ++c) {
                bf16x8 bw = *(const bf16x8*)(w_proj + (colbase + c * 16 + l16) * 256 + kb * 32 + lk);
                #pragma unroll
                for (int rt = 0; rt < 4; ++rt)
                    acc[rt][c] = __builtin_amdgcn_mfma_f32_16x16x32_bf16(
                        a[rt], bw, acc[rt][c], 0, 0, 0);
            }
        }
        float* ob = out + (size_t)b * (NTOK * 256);
        #pragma unroll
        for (int c = 0; c < 2; ++c) {
            const int col = colbase + c * 16 + l16;
            const float pb = proj_b[col];
            // rows rt*16 + 4g + r: rt 0..2 -> rows <= 47, always valid
            #pragma unroll
            for (int rt = 0; rt < 3; ++rt)
                #pragma unroll
                for (int r = 0; r < 4; ++r)
                    ob[(rt * 16 + 4 * g + r) * 256 + col] = acc[rt][c][r] + pb;
            // rt==3: only row 48 (g==0, r==0) is a real token
            if (g == 0) ob[48 * 256 + col] = acc[3][c][0] + pb;
        }
    }
}

extern "C" void kernel_launch(void* const* d_in, const int* in_sizes, int n_in,
                              void* d_out, int out_size, void* d_ws, size_t ws_size,
                              hipStream_t stream) {
    const float* x          = (const float*)d_in[0];
    const float* qkv_w      = (const float*)d_in[1];
    const float* qkv_b      = (const float*)d_in[2];
    const float* proj_w     = (const float*)d_in[3];
    const float* proj_b     = (const float*)d_in[4];
    const float* bias_table = (const float*)d_in[5];

    unsigned short* w_qkv  = (unsigned short*)d_ws;      // 196608 bf16
    unsigned short* w_proj = w_qkv + 196608;             // 65536 bf16
    float*          bias_p = (float*)(w_proj + 65536);   // 32768 f32
    float*          sbias  = bias_p + 32768;             // 768 f32

    prep_kernel<<<288, 256, 0, stream>>>(qkv_w, proj_w, bias_table, qkv_b,
                                         w_qkv, w_proj, bias_p, sbias);

    const int SMEM = (64 * 264 + 8 * 64 * 36) * 2;       // 70656 B
    hipFuncSetAttribute(reinterpret_cast<const void*>(wattn_kernel),
                        hipFuncAttributeMaxDynamicSharedMemorySize, SMEM);

    wattn_kernel<<<8192, 512, SMEM, stream>>>(x, w_qkv, w_proj, bias_p, sbias,
                                              proj_b, (float*)d_out);
}

// Round 10
// 604.299 us; speedup vs baseline: 1.3813x; 1.0011x over previous
//
#include <hip/hip_runtime.h>
#include <hip/hip_bf16.h>
#include <stdint.h>

#define NTOK 49
#define SCALE 0.17677669529663687f
#define LOG2E 1.4426950408889634f

typedef __attribute__((ext_vector_type(8))) short bf16x8;
typedef __attribute__((ext_vector_type(4))) float f32x4;

__device__ __forceinline__ unsigned short f2bf(float f) {
    union { float f; unsigned int u; } v; v.f = f;
    unsigned int r = v.u + 0x7FFFu + ((v.u >> 16) & 1u);
    return (unsigned short)(r >> 16);
}

__device__ __forceinline__ uint32_t pkbf(float lo, float hi) {
    __hip_bfloat162 h = __float22bfloat162_rn(float2{lo, hi});
    union { __hip_bfloat162 h; uint32_t u; } c; c.h = h;
    return c.u;
}

// ---- prep: bf16 weights (Q rows pre-scaled by SCALE*LOG2E for exp2 softmax),
// ---- bias in [h][j/4][i][j%4] layout scaled by LOG2E, scaled qkv bias copy ----
__global__ void prep_kernel(const float* __restrict__ qkv_w,
                            const float* __restrict__ proj_w,
                            const float* __restrict__ bias_table,
                            const float* __restrict__ qkv_b,
                            unsigned short* __restrict__ w_qkv,
                            unsigned short* __restrict__ w_proj,
                            float* __restrict__ bias_p,
                            float* __restrict__ sbias) {
    const int total = 196608 + 65536 + 32768 + 768;
    for (int i = blockIdx.x * blockDim.x + threadIdx.x; i < total;
         i += gridDim.x * blockDim.x) {
        if (i < 196608) {
            float s = (i < 65536) ? SCALE * LOG2E : 1.0f;   // Q rows pre-scaled
            w_qkv[i] = f2bf(qkv_w[i] * s);
        } else if (i < 262144) {
            w_proj[i - 196608] = f2bf(proj_w[i - 196608]);
        } else if (i < 294912) {
            int idx = i - 262144;
            int hh = idx >> 12;             // head
            int j  = (idx >> 6) & 63;       // key token
            int ii = idx & 63;              // query token
            float v;
            if (j >= NTOK)       v = -1e30f;            // mask padded keys
            else if (ii >= NTOK) v = 0.0f;              // garbage queries: finite
            else {
                int rel = (ii / 7 - j / 7 + 6) * 13 + (ii % 7 - j % 7 + 6);
                v = bias_table[rel * 8 + hh];
            }
            // layout: [h][j>>2][ii][j&3] -> float4 over r=j&3; LOG2E folded
            bias_p[hh * 4096 + (j >> 2) * 256 + ii * 4 + (j & 3)] = v * LOG2E;
        } else {
            int r = i - 294912;
            sbias[r] = qkv_b[r] * (r < 256 ? SCALE * LOG2E : 1.0f);
        }
    }
}

// ---- fused window attention: one window/block, 8 waves, 1 head/wave ----
// LDS: sX [64][264] bf16 (33792 B, O written back post-attention) +
// per-wave scratch [64][36] bf16 (4608 B x 8). Total 70656 B.
// Occupancy is REG-limited: 64 VGPR + 64 AGPR = 128 -> 16 waves/CU max.
// So optimize per-wave issue: merged Q+K GEMM (acc[4][4]=64 AGPR, unroll 2
// to avoid R5's hoist-spills), exp2 softmax (LOG2E pre-folded), static loops.
__global__ __launch_bounds__(512, 4) void wattn_kernel(
    const float* __restrict__ x,
    const unsigned short* __restrict__ w_qkv,
    const unsigned short* __restrict__ w_proj,
    const float* __restrict__ bias_p,
    const float* __restrict__ sbias,
    const float* __restrict__ proj_b,
    float* __restrict__ out)
{
    extern __shared__ char smem[];
    unsigned short* sX = (unsigned short*)smem;       // 64*264 elems
    unsigned short* scrBase = sX + 64 * 264;

    const int tid  = threadIdx.x;
    const int wv   = tid >> 6;
    const int lane = tid & 63;
    const int l16  = lane & 15;
    const int g    = lane >> 4;
    const int lk   = g * 8;

    unsigned short* scr = scrBase + wv * (64 * 36);   // [64][36] per wave
    const int b = blockIdx.x;
    const int h = wv;
    const f32x4 fz = {0.f, 0.f, 0.f, 0.f};

    // ---------- stage x -> LDS bf16 (static trip counts), zero pad rows ----------
    const float* xb = x + (size_t)b * (NTOK * 256);
    #pragma unroll
    for (int it = 0; it < 6; ++it) {
        const int idx = tid * 4 + it * 2048;          // < 12288 always valid
        float4 v = *(const float4*)(xb + idx);
        int r = idx >> 8, c = idx & 255;
        *(uint2*)(sX + r * 264 + c) = make_uint2(pkbf(v.x, v.y), pkbf(v.z, v.w));
    }
    if (tid < 64) {                                    // tail: 12288..12543
        const int idx = tid * 4 + 12288;
        float4 v = *(const float4*)(xb + idx);
        int r = idx >> 8, c = idx & 255;
        *(uint2*)(sX + r * 264 + c) = make_uint2(pkbf(v.x, v.y), pkbf(v.z, v.w));
    }
    {                                                  // zero rows 49..63 (3840 elems)
        const int i0 = tid * 4;
        *(uint2*)(sX + (49 + (i0 >> 8)) * 264 + (i0 & 255)) = make_uint2(0, 0);
        const int i1 = i0 + 2048;
        if (i1 < 3840)
            *(uint2*)(sX + (49 + (i1 >> 8)) * 264 + (i1 & 255)) = make_uint2(0, 0);
    }
    __syncthreads();

    bf16x8 qf[4], kf[4], vf[2][2];

    // ---------- merged Q+K GEMM (C = [Q;K]^T, 64 feat x 64 tok) ----------
    // acc[4][4] = 64 AGPR; unroll 2 caps hoisted loads (R7 lesson: no spills)
    {
        f32x4 acc[4][4];
        #pragma unroll
        for (int mt = 0; mt < 4; ++mt)
            #pragma unroll
            for (int nt = 0; nt < 4; ++nt) acc[mt][nt] = fz;

        #pragma unroll 2
        for (int kb = 0; kb < 8; ++kb) {
            bf16x8 bx[4];
            #pragma unroll
            for (int nt = 0; nt < 4; ++nt)
                bx[nt] = *(const bf16x8*)(sX + (nt * 16 + l16) * 264 + kb * 32 + lk);
            #pragma unroll
            for (int mt = 0; mt < 4; ++mt) {
                const int wrow = (mt < 2) ? (h * 32 + mt * 16 + l16)
                                          : (256 + h * 32 + (mt - 2) * 16 + l16);
                bf16x8 aw = *(const bf16x8*)(w_qkv + wrow * 256 + kb * 32 + lk);
                #pragma unroll
                for (int nt = 0; nt < 4; ++nt)
                    acc[mt][nt] = __builtin_amdgcn_mfma_f32_16x16x32_bf16(
                        aw, bx[nt], acc[mt][nt], 0, 0, 0);
            }
        }
        // Q bias (pre-scaled); K bias dropped (softmax-invariant)
        float4 bq0 = *(const float4*)(sbias + h * 32 + 4 * g);
        float4 bq1 = *(const float4*)(sbias + h * 32 + 16 + 4 * g);
        #pragma unroll
        for (int nt = 0; nt < 4; ++nt) {
            acc[0][nt][0] += bq0.x; acc[0][nt][1] += bq0.y;
            acc[0][nt][2] += bq0.z; acc[0][nt][3] += bq0.w;
            acc[1][nt][0] += bq1.x; acc[1][nt][1] += bq1.y;
            acc[1][nt][2] += bq1.z; acc[1][nt][3] += bq1.w;
        }
        // Q bounce (mt 0-1): [token][feat] in scr[64][36]
        #pragma unroll
        for (int nt = 0; nt < 4; ++nt)
            #pragma unroll
            for (int mt = 0; mt < 2; ++mt) {
                uint2 d = make_uint2(pkbf(acc[mt][nt][0], acc[mt][nt][1]),
                                     pkbf(acc[mt][nt][2], acc[mt][nt][3]));
                *(uint2*)(scr + (nt * 16 + l16) * 36 + mt * 16 + 4 * g) = d;
            }
        #pragma unroll
        for (int nt = 0; nt < 4; ++nt)
            qf[nt] = *(const bf16x8*)(scr + (nt * 16 + l16) * 36 + lk);
        // K bounce (mt 2-3): same slots; DS in-wave ordering keeps qf reads safe
        #pragma unroll
        for (int nt = 0; nt < 4; ++nt)
            #pragma unroll
            for (int mt = 2; mt < 4; ++mt) {
                uint2 d = make_uint2(pkbf(acc[mt][nt][0], acc[mt][nt][1]),
                                     pkbf(acc[mt][nt][2], acc[mt][nt][3]));
                *(uint2*)(scr + (nt * 16 + l16) * 36 + (mt - 2) * 16 + 4 * g) = d;
            }
        #pragma unroll
        for (int nt = 0; nt < 4; ++nt)
            kf[nt] = *(const bf16x8*)(scr + (nt * 16 + l16) * 36 + lk);
    }

    // ---------- V-GEMM (normal: C = V, 64 tok x 32 d) ----------
    {
        f32x4 acc[4][2];
        #pragma unroll
        for (int rt = 0; rt < 4; ++rt) { acc[rt][0] = fz; acc[rt][1] = fz; }

        #pragma unroll 2
        for (int kb = 0; kb < 8; ++kb) {
            bf16x8 ax[4];
            #pragma unroll
            for (int rt = 0; rt < 4; ++rt)
                ax[rt] = *(const bf16x8*)(sX + (rt * 16 + l16) * 264 + kb * 32 + lk);
            #pragma unroll
            for (int ct = 0; ct < 2; ++ct) {
                bf16x8 bw = *(const bf16x8*)(w_qkv + (512 + h * 32 + ct * 16 + l16) * 256 + kb * 32 + lk);
                #pragma unroll
                for (int rt = 0; rt < 4; ++rt)
                    acc[rt][ct] = __builtin_amdgcn_mfma_f32_16x16x32_bf16(
                        ax[rt], bw, acc[rt][ct], 0, 0, 0);
            }
        }
        // V^T bounce: rows = kk*32 + d (disjoint halves), cols = tok%32
        #pragma unroll
        for (int rt = 0; rt < 4; ++rt)
            #pragma unroll
            for (int ct = 0; ct < 2; ++ct) {
                uint2 d = make_uint2(pkbf(acc[rt][ct][0], acc[rt][ct][1]),
                                     pkbf(acc[rt][ct][2], acc[rt][ct][3]));
                *(uint2*)(scr + ((rt >> 1) * 32 + ct * 16 + l16) * 36 + (rt & 1) * 16 + 4 * g) = d;
            }
        #pragma unroll
        for (int dm = 0; dm < 2; ++dm)
            #pragma unroll
            for (int kk = 0; kk < 2; ++kk)
                vf[dm][kk] = *(const bf16x8*)(scr + (kk * 32 + dm * 16 + l16) * 36 + lk);
    }
    // NO barrier: attention touches only per-wave scr + global bias.

    // ---------- attention (barrier-free, per-wave head), 2 query halves ----------
    const float* bp_h = bias_p + h * 4096;
    float4 bv0 = *(const float4*)(sbias + 512 + h * 32 + 4 * g);
    float4 bv1 = *(const float4*)(sbias + 512 + h * 32 + 16 + 4 * g);

    uint2 o_st[2][2][2];   // [hf][dm][tl] packed bf16 O, written to sX later

    #pragma unroll
    for (int hf = 0; hf < 2; ++hf) {
        // S^T acc init from pre-masked bias (one dwordx4 per tile-row), 8 mfma
        f32x4 s[4][2];
        #pragma unroll
        for (int tr = 0; tr < 4; ++tr)
            #pragma unroll
            for (int tl = 0; tl < 2; ++tl) {
                const int i = (hf * 2 + tl) * 16 + l16;
                s[tr][tl] = *(const f32x4*)(bp_h + (tr * 4 + g) * 256 + i * 4);
            }
        __builtin_amdgcn_s_setprio(1);
        #pragma unroll
        for (int tr = 0; tr < 4; ++tr)
            #pragma unroll
            for (int tl = 0; tl < 2; ++tl)
                s[tr][tl] = __builtin_amdgcn_mfma_f32_16x16x32_bf16(
                    kf[tr], qf[hf * 2 + tl], s[tr][tl], 0, 0, 0);
        __builtin_amdgcn_s_setprio(0);

        // softmax in base-2 (LOG2E pre-folded into W_q, bq, bias) —
        // raw v_exp_f32, no max-subtraction (|S| small; masked -> 0)
        float inv[2];
        #pragma unroll
        for (int tl = 0; tl < 2; ++tl) {
            float s4[4];
            #pragma unroll
            for (int tr = 0; tr < 4; ++tr) {
                float e0 = __builtin_amdgcn_exp2f(s[tr][tl][0]);
                float e1 = __builtin_amdgcn_exp2f(s[tr][tl][1]);
                float e2 = __builtin_amdgcn_exp2f(s[tr][tl][2]);
                float e3 = __builtin_amdgcn_exp2f(s[tr][tl][3]);
                s[tr][tl][0] = e0; s[tr][tl][1] = e1;
                s[tr][tl][2] = e2; s[tr][tl][3] = e3;
                s4[tr] = (e0 + e1) + (e2 + e3);
            }
            float sum = (s4[0] + s4[1]) + (s4[2] + s4[3]);
            sum += __shfl_xor(sum, 16);
            sum += __shfl_xor(sum, 32);
            inv[tl] = 1.0f / sum;
        }

        // P bounce: rows = kk*32 + i (disjoint halves), cols = j%32
        #pragma unroll
        for (int tr = 0; tr < 4; ++tr)
            #pragma unroll
            for (int tl = 0; tl < 2; ++tl) {
                uint2 d = make_uint2(pkbf(s[tr][tl][0], s[tr][tl][1]),
                                     pkbf(s[tr][tl][2], s[tr][tl][3]));
                *(uint2*)(scr + ((tr >> 1) * 32 + tl * 16 + l16) * 36 + (tr & 1) * 16 + 4 * g) = d;
            }
        bf16x8 pf[2][2];
        #pragma unroll
        for (int tl = 0; tl < 2; ++tl)
            #pragma unroll
            for (int kk = 0; kk < 2; ++kk)
                pf[tl][kk] = *(const bf16x8*)(scr + (kk * 32 + tl * 16 + l16) * 36 + lk);

        // O^T = V^T P  (unnormalized P; scale by inv afterwards)
        f32x4 o[2][2];
        #pragma unroll
        for (int dm = 0; dm < 2; ++dm) { o[dm][0] = fz; o[dm][1] = fz; }
        __builtin_amdgcn_s_setprio(1);
        #pragma unroll
        for (int dm = 0; dm < 2; ++dm)
            #pragma unroll
            for (int tl = 0; tl < 2; ++tl)
                #pragma unroll
                for (int kk = 0; kk < 2; ++kk)
                    o[dm][tl] = __builtin_amdgcn_mfma_f32_16x16x32_bf16(
                        vf[dm][kk], pf[tl][kk], o[dm][tl], 0, 0, 0);
        __builtin_amdgcn_s_setprio(0);

        // epilogue: *inv, +bv, pack into registers (written to sX post-barrier)
        #pragma unroll
        for (int dm = 0; dm < 2; ++dm) {
            const float4 bv = dm ? bv1 : bv0;
            #pragma unroll
            for (int tl = 0; tl < 2; ++tl) {
                const float iv = inv[tl];
                float r0 = o[dm][tl][0] * iv + bv.x;
                float r1 = o[dm][tl][1] * iv + bv.y;
                float r2 = o[dm][tl][2] * iv + bv.z;
                float r3 = o[dm][tl][3] * iv + bv.w;
                o_st[hf][dm][tl] = make_uint2(pkbf(r0, r1), pkbf(r2, r3));
            }
        }
    }

    __syncthreads();   // all waves done reading sX (V-GEMM) -> overlay safe

    // ---------- write O regs -> sX ----------
    #pragma unroll
    for (int hf = 0; hf < 2; ++hf)
        #pragma unroll
        for (int dm = 0; dm < 2; ++dm)
            #pragma unroll
            for (int tl = 0; tl < 2; ++tl)
                *(uint2*)(sX + ((hf * 2 + tl) * 16 + l16) * 264 + h * 32 + dm * 16 + 4 * g)
                    = o_st[hf][dm][tl];
    __syncthreads();

    // ---------- proj GEMM (64x256, K=256), wave owns 32 cols ----------
    {
        f32x4 acc[4][2];
        #pragma unroll
        for (int rt = 0; rt < 4; ++rt) { acc[rt][0] = fz; acc[rt][1] = fz; }

        const int colbase = wv * 32;
        #pragma unroll 2
        for (int kb = 0; kb < 8; ++kb) {
            bf16x8 a[4];
            #pragma unroll
            for (int rt = 0; rt < 4; ++rt)
                a[rt] = *(const bf16x8*)(sX + (rt * 16 + l16) * 264 + kb * 32 + lk);
            #pragma unroll
            for (int c = 0; c < 2; ++c) {
                bf16x8 bw = *(const bf16x8*)(w_proj + (colbase + c * 16 + l16) * 256 + kb * 32 + lk);
                #pragma unroll
                for (int rt = 0; rt < 4; ++rt)
                    acc[rt][c] = __builtin_amdgcn_mfma_f32_16x16x32_bf16(
                        a[rt], bw, acc[rt][c], 0, 0, 0);
            }
        }
        float* ob = out + (size_t)b * (NTOK * 256);
        #pragma unroll
        for (int c = 0; c < 2; ++c) {
            const int col = colbase + c * 16 + l16;
            const float pb = proj_b[col];
            // rows rt*16 + 4g + r: rt 0..2 -> rows <= 47, always valid
            #pragma unroll
            for (int rt = 0; rt < 3; ++rt)
                #pragma unroll
                for (int r = 0; r < 4; ++r)
                    ob[(rt * 16 + 4 * g + r) * 256 + col] = acc[rt][c][r] + pb;
            // rt==3: only row 48 (g==0, r==0) is a real token
            if (g == 0) ob[48 * 256 + col] = acc[3][c][0] + pb;
        }
    }
}

extern "C" void kernel_launch(void* const* d_in, const int* in_sizes, int n_in,
                              void* d_out, int out_size, void* d_ws, size_t ws_size,
                              hipStream_t stream) {
    const float* x          = (const float*)d_in[0];
    const float* qkv_w      = (const float*)d_in[1];
    const float* qkv_b      = (const float*)d_in[2];
    const float* proj_w     = (const float*)d_in[3];
    const float* proj_b     = (const float*)d_in[4];
    const float* bias_table = (const float*)d_in[5];

    unsigned short* w_qkv  = (unsigned short*)d_ws;      // 196608 bf16
    unsigned short* w_proj = w_qkv + 196608;             // 65536 bf16
    float*          bias_p = (float*)(w_proj + 65536);   // 32768 f32
    float*          sbias  = bias_p + 32768;             // 768 f32

    prep_kernel<<<288, 256, 0, stream>>>(qkv_w, proj_w, bias_table, qkv_b,
                                         w_qkv, w_proj, bias_p, sbias);

    const int SMEM = (64 * 264 + 8 * 64 * 36) * 2;       // 70656 B
    hipFuncSetAttribute(reinterpret_cast<const void*>(wattn_kernel),
                        hipFuncAttributeMaxDynamicSharedMemorySize, SMEM);

    wattn_kernel<<<8192, 512, SMEM, stream>>>(x, w_qkv, w_proj, bias_p, sbias,
                                              proj_b, (float*)d_out);
}

// Round 11
// 588.140 us; speedup vs baseline: 1.4193x; 1.0275x over previous
//
#include <hip/hip_runtime.h>
#include <hip/hip_bf16.h>
#include <stdint.h>

#define NTOK 49
#define SCALE 0.17677669529663687f
#define LOG2E 1.4426950408889634f

typedef __attribute__((ext_vector_type(8))) short bf16x8;
typedef __attribute__((ext_vector_type(4))) float f32x4;

__device__ __forceinline__ unsigned short f2bf(float f) {
    union { float f; unsigned int u; } v; v.f = f;
    unsigned int r = v.u + 0x7FFFu + ((v.u >> 16) & 1u);
    return (unsigned short)(r >> 16);
}

__device__ __forceinline__ uint32_t pkbf(float lo, float hi) {
    __hip_bfloat162 h = __float22bfloat162_rn(float2{lo, hi});
    union { __hip_bfloat162 h; uint32_t u; } c; c.h = h;
    return c.u;
}

// ---- prep: bf16 weights (Q rows pre-scaled by SCALE*LOG2E for exp2 softmax),
// ---- bias in [h][j/4][i][j%4] layout scaled by LOG2E, scaled qkv bias copy ----
__global__ void prep_kernel(const float* __restrict__ qkv_w,
                            const float* __restrict__ proj_w,
                            const float* __restrict__ bias_table,
                            const float* __restrict__ qkv_b,
                            unsigned short* __restrict__ w_qkv,
                            unsigned short* __restrict__ w_proj,
                            float* __restrict__ bias_p,
                            float* __restrict__ sbias) {
    const int total = 196608 + 65536 + 32768 + 768;
    for (int i = blockIdx.x * blockDim.x + threadIdx.x; i < total;
         i += gridDim.x * blockDim.x) {
        if (i < 196608) {
            float s = (i < 65536) ? SCALE * LOG2E : 1.0f;   // Q rows pre-scaled
            w_qkv[i] = f2bf(qkv_w[i] * s);
        } else if (i < 262144) {
            w_proj[i - 196608] = f2bf(proj_w[i - 196608]);
        } else if (i < 294912) {
            int idx = i - 262144;
            int hh = idx >> 12;             // head
            int j  = (idx >> 6) & 63;       // key token
            int ii = idx & 63;              // query token
            float v;
            if (j >= NTOK)       v = -1e30f;            // mask padded keys
            else if (ii >= NTOK) v = 0.0f;              // garbage queries: finite
            else {
                int rel = (ii / 7 - j / 7 + 6) * 13 + (ii % 7 - j % 7 + 6);
                v = bias_table[rel * 8 + hh];
            }
            // layout: [h][j>>2][ii][j&3] -> float4 over r=j&3; LOG2E folded
            bias_p[hh * 4096 + (j >> 2) * 256 + ii * 4 + (j & 3)] = v * LOG2E;
        } else {
            int r = i - 294912;
            sbias[r] = qkv_b[r] * (r < 256 ? SCALE * LOG2E : 1.0f);
        }
    }
}

// ---- fused window attention: one window/block, 8 waves, 1 head/wave ----
// LDS: sX [64][264] bf16 (33792 B, O written back post-attention) +
// per-wave scratch [64][36] bf16 (4608 B x 8). Total 70656 B.
// Occupancy REG+LDS capped at 16 waves/CU; optimize per-wave serial chain:
// unroll-1 GEMM k-loops with 1-deep rotation prefetch of weight fragments
// (global loads issue BEFORE the dependent MFMAs of the previous k-step ->
// L2 latency covered; vmcnt(4) at MFMA = no wait). Also ~2x smaller code.
__global__ __launch_bounds__(512, 4) void wattn_kernel(
    const float* __restrict__ x,
    const unsigned short* __restrict__ w_qkv,
    const unsigned short* __restrict__ w_proj,
    const float* __restrict__ bias_p,
    const float* __restrict__ sbias,
    const float* __restrict__ proj_b,
    float* __restrict__ out)
{
    extern __shared__ char smem[];
    unsigned short* sX = (unsigned short*)smem;       // 64*264 elems
    unsigned short* scrBase = sX + 64 * 264;

    const int tid  = threadIdx.x;
    const int wv   = tid >> 6;
    const int lane = tid & 63;
    const int l16  = lane & 15;
    const int g    = lane >> 4;
    const int lk   = g * 8;

    unsigned short* scr = scrBase + wv * (64 * 36);   // [64][36] per wave
    const int b = blockIdx.x;
    const int h = wv;
    const f32x4 fz = {0.f, 0.f, 0.f, 0.f};

    // ---------- stage x -> LDS bf16 (16B stores), zero pad rows ----------
    const float* xb = x + (size_t)b * (NTOK * 256);
    #pragma unroll
    for (int it = 0; it < 3; ++it) {
        const int idx = tid * 8 + it * 4096;          // < 12288 always valid
        float4 v0 = *(const float4*)(xb + idx);
        float4 v1 = *(const float4*)(xb + idx + 4);
        int r = idx >> 8, c = idx & 255;
        *(uint4*)(sX + r * 264 + c) = make_uint4(pkbf(v0.x, v0.y), pkbf(v0.z, v0.w),
                                                 pkbf(v1.x, v1.y), pkbf(v1.z, v1.w));
    }
    if (tid < 32) {                                    // tail: 12288..12543
        const int idx = 12288 + tid * 8;
        float4 v0 = *(const float4*)(xb + idx);
        float4 v1 = *(const float4*)(xb + idx + 4);
        int r = idx >> 8, c = idx & 255;
        *(uint4*)(sX + r * 264 + c) = make_uint4(pkbf(v0.x, v0.y), pkbf(v0.z, v0.w),
                                                 pkbf(v1.x, v1.y), pkbf(v1.z, v1.w));
    }
    if (tid < 480) {                                   // zero rows 49..63
        const int idx = tid * 8;
        *(uint4*)(sX + (49 + (idx >> 8)) * 264 + (idx & 255)) = make_uint4(0, 0, 0, 0);
    }
    __syncthreads();

    bf16x8 qf[4], kf[4], vf[2][2];

    // ---------- merged Q+K GEMM (C = [Q;K]^T, 64 feat x 64 tok) ----------
    // unroll-1 + 1-deep weight rotation: awn[kb+1] issued before mfma[kb]
    {
        f32x4 acc[4][4];
        #pragma unroll
        for (int mt = 0; mt < 4; ++mt)
            #pragma unroll
            for (int nt = 0; nt < 4; ++nt) acc[mt][nt] = fz;

        const unsigned short* wp[4];
        wp[0] = w_qkv + (h * 32 + l16) * 256 + lk;
        wp[1] = wp[0] + 16 * 256;
        wp[2] = wp[0] + 256 * 256;
        wp[3] = wp[2] + 16 * 256;

        bf16x8 awc[4], awn[4];
        #pragma unroll
        for (int mt = 0; mt < 4; ++mt) awc[mt] = *(const bf16x8*)(wp[mt]);

        #pragma unroll 1
        for (int kb = 0; kb < 8; ++kb) {
            const int kn = ((kb + 1) & 7) * 32;
            #pragma unroll
            for (int mt = 0; mt < 4; ++mt)
                awn[mt] = *(const bf16x8*)(wp[mt] + kn);
            bf16x8 bx[4];
            #pragma unroll
            for (int nt = 0; nt < 4; ++nt)
                bx[nt] = *(const bf16x8*)(sX + (nt * 16 + l16) * 264 + kb * 32 + lk);
            #pragma unroll
            for (int mt = 0; mt < 4; ++mt)
                #pragma unroll
                for (int nt = 0; nt < 4; ++nt)
                    acc[mt][nt] = __builtin_amdgcn_mfma_f32_16x16x32_bf16(
                        awc[mt], bx[nt], acc[mt][nt], 0, 0, 0);
            #pragma unroll
            for (int mt = 0; mt < 4; ++mt) awc[mt] = awn[mt];
        }

        // Q bias (pre-scaled); K bias dropped (softmax-invariant)
        float4 bq0 = *(const float4*)(sbias + h * 32 + 4 * g);
        float4 bq1 = *(const float4*)(sbias + h * 32 + 16 + 4 * g);
        #pragma unroll
        for (int nt = 0; nt < 4; ++nt) {
            acc[0][nt][0] += bq0.x; acc[0][nt][1] += bq0.y;
            acc[0][nt][2] += bq0.z; acc[0][nt][3] += bq0.w;
            acc[1][nt][0] += bq1.x; acc[1][nt][1] += bq1.y;
            acc[1][nt][2] += bq1.z; acc[1][nt][3] += bq1.w;
        }
        // Q bounce (mt 0-1): [token][feat] in scr[64][36]
        #pragma unroll
        for (int nt = 0; nt < 4; ++nt)
            #pragma unroll
            for (int mt = 0; mt < 2; ++mt) {
                uint2 d = make_uint2(pkbf(acc[mt][nt][0], acc[mt][nt][1]),
                                     pkbf(acc[mt][nt][2], acc[mt][nt][3]));
                *(uint2*)(scr + (nt * 16 + l16) * 36 + mt * 16 + 4 * g) = d;
            }
        #pragma unroll
        for (int nt = 0; nt < 4; ++nt)
            qf[nt] = *(const bf16x8*)(scr + (nt * 16 + l16) * 36 + lk);
        // K bounce (mt 2-3): same slots; in-wave DS ordering keeps qf reads safe
        #pragma unroll
        for (int nt = 0; nt < 4; ++nt)
            #pragma unroll
            for (int mt = 2; mt < 4; ++mt) {
                uint2 d = make_uint2(pkbf(acc[mt][nt][0], acc[mt][nt][1]),
                                     pkbf(acc[mt][nt][2], acc[mt][nt][3]));
                *(uint2*)(scr + (nt * 16 + l16) * 36 + (mt - 2) * 16 + 4 * g) = d;
            }
        #pragma unroll
        for (int nt = 0; nt < 4; ++nt)
            kf[nt] = *(const bf16x8*)(scr + (nt * 16 + l16) * 36 + lk);
    }

    // ---------- V-GEMM (normal: C = V, 64 tok x 32 d), same rotation ----------
    {
        f32x4 acc[4][2];
        #pragma unroll
        for (int rt = 0; rt < 4; ++rt) { acc[rt][0] = fz; acc[rt][1] = fz; }

        const unsigned short* vp0 = w_qkv + (512 + h * 32 + l16) * 256 + lk;
        const unsigned short* vp1 = vp0 + 16 * 256;

        bf16x8 bwc[2], bwn[2];
        bwc[0] = *(const bf16x8*)(vp0);
        bwc[1] = *(const bf16x8*)(vp1);

        #pragma unroll 1
        for (int kb = 0; kb < 8; ++kb) {
            const int kn = ((kb + 1) & 7) * 32;
            bwn[0] = *(const bf16x8*)(vp0 + kn);
            bwn[1] = *(const bf16x8*)(vp1 + kn);
            bf16x8 ax[4];
            #pragma unroll
            for (int rt = 0; rt < 4; ++rt)
                ax[rt] = *(const bf16x8*)(sX + (rt * 16 + l16) * 264 + kb * 32 + lk);
            #pragma unroll
            for (int ct = 0; ct < 2; ++ct)
                #pragma unroll
                for (int rt = 0; rt < 4; ++rt)
                    acc[rt][ct] = __builtin_amdgcn_mfma_f32_16x16x32_bf16(
                        ax[rt], bwc[ct], acc[rt][ct], 0, 0, 0);
            bwc[0] = bwn[0]; bwc[1] = bwn[1];
        }
        // V^T bounce: rows = kk*32 + d (disjoint halves), cols = tok%32
        #pragma unroll
        for (int rt = 0; rt < 4; ++rt)
            #pragma unroll
            for (int ct = 0; ct < 2; ++ct) {
                uint2 d = make_uint2(pkbf(acc[rt][ct][0], acc[rt][ct][1]),
                                     pkbf(acc[rt][ct][2], acc[rt][ct][3]));
                *(uint2*)(scr + ((rt >> 1) * 32 + ct * 16 + l16) * 36 + (rt & 1) * 16 + 4 * g) = d;
            }
        #pragma unroll
        for (int dm = 0; dm < 2; ++dm)
            #pragma unroll
            for (int kk = 0; kk < 2; ++kk)
                vf[dm][kk] = *(const bf16x8*)(scr + (kk * 32 + dm * 16 + l16) * 36 + lk);
    }
    // NO barrier: attention touches only per-wave scr + global bias.

    // ---------- attention (barrier-free, per-wave head), 2 query halves ----------
    const float* bp_h = bias_p + h * 4096;
    float4 bv0 = *(const float4*)(sbias + 512 + h * 32 + 4 * g);
    float4 bv1 = *(const float4*)(sbias + 512 + h * 32 + 16 + 4 * g);

    uint2 o_st[2][2][2];   // [hf][dm][tl] packed bf16 O, written to sX later

    #pragma unroll
    for (int hf = 0; hf < 2; ++hf) {
        // S^T acc init from pre-masked bias (one dwordx4 per tile-row), 8 mfma
        f32x4 s[4][2];
        #pragma unroll
        for (int tr = 0; tr < 4; ++tr)
            #pragma unroll
            for (int tl = 0; tl < 2; ++tl) {
                const int i = (hf * 2 + tl) * 16 + l16;
                s[tr][tl] = *(const f32x4*)(bp_h + (tr * 4 + g) * 256 + i * 4);
            }
        __builtin_amdgcn_s_setprio(1);
        #pragma unroll
        for (int tr = 0; tr < 4; ++tr)
            #pragma unroll
            for (int tl = 0; tl < 2; ++tl)
                s[tr][tl] = __builtin_amdgcn_mfma_f32_16x16x32_bf16(
                    kf[tr], qf[hf * 2 + tl], s[tr][tl], 0, 0, 0);
        __builtin_amdgcn_s_setprio(0);

        // softmax in base-2 (LOG2E pre-folded into W_q, bq, bias) —
        // raw v_exp_f32, no max-subtraction (|S| small; masked -> 0)
        float inv[2];
        #pragma unroll
        for (int tl = 0; tl < 2; ++tl) {
            float s4[4];
            #pragma unroll
            for (int tr = 0; tr < 4; ++tr) {
                float e0 = __builtin_amdgcn_exp2f(s[tr][tl][0]);
                float e1 = __builtin_amdgcn_exp2f(s[tr][tl][1]);
                float e2 = __builtin_amdgcn_exp2f(s[tr][tl][2]);
                float e3 = __builtin_amdgcn_exp2f(s[tr][tl][3]);
                s[tr][tl][0] = e0; s[tr][tl][1] = e1;
                s[tr][tl][2] = e2; s[tr][tl][3] = e3;
                s4[tr] = (e0 + e1) + (e2 + e3);
            }
            float sum = (s4[0] + s4[1]) + (s4[2] + s4[3]);
            sum += __shfl_xor(sum, 16);
            sum += __shfl_xor(sum, 32);
            inv[tl] = 1.0f / sum;
        }

        // P bounce: rows = kk*32 + i (disjoint halves), cols = j%32
        #pragma unroll
        for (int tr = 0; tr < 4; ++tr)
            #pragma unroll
            for (int tl = 0; tl < 2; ++tl) {
                uint2 d = make_uint2(pkbf(s[tr][tl][0], s[tr][tl][1]),
                                     pkbf(s[tr][tl][2], s[tr][tl][3]));
                *(uint2*)(scr + ((tr >> 1) * 32 + tl * 16 + l16) * 36 + (tr & 1) * 16 + 4 * g) = d;
            }
        bf16x8 pf[2][2];
        #pragma unroll
        for (int tl = 0; tl < 2; ++tl)
            #pragma unroll
            for (int kk = 0; kk < 2; ++kk)
                pf[tl][kk] = *(const bf16x8*)(scr + (kk * 32 + tl * 16 + l16) * 36 + lk);

        // O^T = V^T P  (unnormalized P; scale by inv afterwards)
        f32x4 o[2][2];
        #pragma unroll
        for (int dm = 0; dm < 2; ++dm) { o[dm][0] = fz; o[dm][1] = fz; }
        __builtin_amdgcn_s_setprio(1);
        #pragma unroll
        for (int dm = 0; dm < 2; ++dm)
            #pragma unroll
            for (int tl = 0; tl < 2; ++tl)
                #pragma unroll
                for (int kk = 0; kk < 2; ++kk)
                    o[dm][tl] = __builtin_amdgcn_mfma_f32_16x16x32_bf16(
                        vf[dm][kk], pf[tl][kk], o[dm][tl], 0, 0, 0);
        __builtin_amdgcn_s_setprio(0);

        // epilogue: *inv, +bv, pack into registers (written to sX post-barrier)
        #pragma unroll
        for (int dm = 0; dm < 2; ++dm) {
            const float4 bv = dm ? bv1 : bv0;
            #pragma unroll
            for (int tl = 0; tl < 2; ++tl) {
                const float iv = inv[tl];
                float r0 = o[dm][tl][0] * iv + bv.x;
                float r1 = o[dm][tl][1] * iv + bv.y;
                float r2 = o[dm][tl][2] * iv + bv.z;
                float r3 = o[dm][tl][3] * iv + bv.w;
                o_st[hf][dm][tl] = make_uint2(pkbf(r0, r1), pkbf(r2, r3));
            }
        }
    }

    __syncthreads();   // all waves done reading sX (V-GEMM) -> overlay safe

    // ---------- write O regs -> sX ----------
    #pragma unroll
    for (int hf = 0; hf < 2; ++hf)
        #pragma unroll
        for (int dm = 0; dm < 2; ++dm)
            #pragma unroll
            for (int tl = 0; tl < 2; ++tl)
                *(uint2*)(sX + ((hf * 2 + tl) * 16 + l16) * 264 + h * 32 + dm * 16 + 4 * g)
                    = o_st[hf][dm][tl];
    __syncthreads();

    // ---------- proj GEMM (64x256, K=256), wave owns 32 cols, rotation ----------
    {
        f32x4 acc[4][2];
        #pragma unroll
        for (int rt = 0; rt < 4; ++rt) { acc[rt][0] = fz; acc[rt][1] = fz; }

        const unsigned short* pp0 = w_proj + (wv * 32 + l16) * 256 + lk;
        const unsigned short* pp1 = pp0 + 16 * 256;

        bf16x8 bwc[2], bwn[2];
        bwc[0] = *(const bf16x8*)(pp0);
        bwc[1] = *(const bf16x8*)(pp1);

        #pragma unroll 1
        for (int kb = 0; kb < 8; ++kb) {
            const int kn = ((kb + 1) & 7) * 32;
            bwn[0] = *(const bf16x8*)(pp0 + kn);
            bwn[1] = *(const bf16x8*)(pp1 + kn);
            bf16x8 a[4];
            #pragma unroll
            for (int rt = 0; rt < 4; ++rt)
                a[rt] = *(const bf16x8*)(sX + (rt * 16 + l16) * 264 + kb * 32 + lk);
            #pragma unroll
            for (int c = 0; c < 2; ++c)
                #pragma unroll
                for (int rt = 0; rt < 4; ++rt)
                    acc[rt][c] = __builtin_amdgcn_mfma_f32_16x16x32_bf16(
                        a[rt], bwc[c], acc[rt][c], 0, 0, 0);
            bwc[0] = bwn[0]; bwc[1] = bwn[1];
        }
        float* ob = out + (size_t)b * (NTOK * 256);
        #pragma unroll
        for (int c = 0; c < 2; ++c) {
            const int col = wv * 32 + c * 16 + l16;
            const float pb = proj_b[col];
            // rows rt*16 + 4g + r: rt 0..2 -> rows <= 47, always valid
            #pragma unroll
            for (int rt = 0; rt < 3; ++rt)
                #pragma unroll
                for (int r = 0; r < 4; ++r)
                    ob[(rt * 16 + 4 * g + r) * 256 + col] = acc[rt][c][r] + pb;
            // rt==3: only row 48 (g==0, r==0) is a real token
            if (g == 0) ob[48 * 256 + col] = acc[3][c][0] + pb;
        }
    }
}

extern "C" void kernel_launch(void* const* d_in, const int* in_sizes, int n_in,
                              void* d_out, int out_size, void* d_ws, size_t ws_size,
                              hipStream_t stream) {
    const float* x          = (const float*)d_in[0];
    const float* qkv_w      = (const float*)d_in[1];
    const float* qkv_b      = (const float*)d_in[2];
    const float* proj_w     = (const float*)d_in[3];
    const float* proj_b     = (const float*)d_in[4];
    const float* bias_table = (const float*)d_in[5];

    unsigned short* w_qkv  = (unsigned short*)d_ws;      // 196608 bf16
    unsigned short* w_proj = w_qkv + 196608;             // 65536 bf16
    float*          bias_p = (float*)(w_proj + 65536);   // 32768 f32
    float*          sbias  = bias_p + 32768;             // 768 f32

    prep_kernel<<<288, 256, 0, stream>>>(qkv_w, proj_w, bias_table, qkv_b,
                                         w_qkv, w_proj, bias_p, sbias);

    const int SMEM = (64 * 264 + 8 * 64 * 36) * 2;       // 70656 B
    hipFuncSetAttribute(reinterpret_cast<const void*>(wattn_kernel),
                        hipFuncAttributeMaxDynamicSharedMemorySize, SMEM);

    wattn_kernel<<<8192, 512, SMEM, stream>>>(x, w_qkv, w_proj, bias_p, sbias,
                                              proj_b, (float*)d_out);
}